// Round 2
// baseline (562.142 us; speedup 1.0000x reference)
//
#include <hip/hip_runtime.h>
#include <stdint.h>

// Problem constants
#define NB 2
#define NS 2048
#define NE 1024
#define NH 16
#define ND 64

typedef __attribute__((ext_vector_type(8))) short short8;
typedef __attribute__((ext_vector_type(4))) float f4;
typedef __attribute__((ext_vector_type(4))) unsigned short us4;

static __device__ __forceinline__ unsigned short bf16_rne(float x) {
  uint32_t u = __builtin_bit_cast(uint32_t, x);
  u += 0x7fffu + ((u >> 16) & 1u);
  return (unsigned short)(u >> 16);
}
static __device__ __forceinline__ float bf16_f32(unsigned short h) {
  uint32_t u = ((uint32_t)h) << 16;
  return __builtin_bit_cast(float, u);
}

// JAX threefry2x32, key = (0, 42), 20 rounds.
static __device__ __forceinline__ void threefry42(uint32_t x0, uint32_t x1,
                                                  uint32_t& o0, uint32_t& o1) {
  const uint32_t ks0 = 0u, ks1 = 42u;
  const uint32_t ks2 = 0u ^ 42u ^ 0x1BD11BDAu;
  x0 += ks0; x1 += ks1;
#define TF4(a,b,c,d) \
  x0 += x1; x1 = __builtin_rotateleft32(x1, a); x1 ^= x0; \
  x0 += x1; x1 = __builtin_rotateleft32(x1, b); x1 ^= x0; \
  x0 += x1; x1 = __builtin_rotateleft32(x1, c); x1 ^= x0; \
  x0 += x1; x1 = __builtin_rotateleft32(x1, d); x1 ^= x0;
  TF4(13,15,26,6)  x0 += ks1; x1 += ks2 + 1u;
  TF4(17,29,16,24) x0 += ks2; x1 += ks0 + 2u;
  TF4(13,15,26,6)  x0 += ks0; x1 += ks1 + 3u;
  TF4(17,29,16,24) x0 += ks1; x1 += ks2 + 4u;
  TF4(13,15,26,6)  x0 += ks2; x1 += ks0 + 5u;
#undef TF4
  o0 = x0; o1 = x1;
}

// async global->LDS 16B/lane.
static __device__ __forceinline__ void gl2lds16(const void* g, void* l) {
  __builtin_amdgcn_global_load_lds(
      (const __attribute__((address_space(1))) uint32_t*)g,
      (__attribute__((address_space(3))) uint32_t*)l, 16, 0, 0);
}

// ---------------- kernel 0: split fp32 -> bf16 hi/lo ----------------
__global__ void k_split(const float* __restrict__ x, const float* __restrict__ qw,
                        const float* __restrict__ ow,
                        unsigned short* __restrict__ xh, unsigned short* __restrict__ xl,
                        unsigned short* __restrict__ wh, unsigned short* __restrict__ wl,
                        unsigned short* __restrict__ woh) {
  for (uint32_t i = blockIdx.x * 256u + threadIdx.x; i < 8388608u; i += gridDim.x * 256u) {
    if (i < 4194304u) {
      float v = x[i];
      unsigned short hi = bf16_rne(v);
      xh[i] = hi;
      xl[i] = bf16_rne(v - bf16_f32(hi));
    } else if (i < 7340032u) {
      uint32_t j = i - 4194304u;
      float v = qw[j];
      unsigned short hi = bf16_rne(v);
      wh[j] = hi;
      wl[j] = bf16_rne(v - bf16_f32(hi));
    } else {
      uint32_t j = i - 7340032u;
      woh[j] = bf16_rne(ow[j]);
    }
  }
}

// ---------------- kernel 1: QKV GEMM, split-bf16 MFMA ----------------
// Q,K blocks (bn<16): 3-pass split-bf16, hi/lo outputs.
// V blocks (bn>=16): 1-pass bf16, epilogue LDS-transpose -> coalesced Vt stores.
__global__ __launch_bounds__(256) void k_qkv(
    const unsigned short* __restrict__ xh, const unsigned short* __restrict__ xl,
    const unsigned short* __restrict__ wh, const unsigned short* __restrict__ wl,
    const float* __restrict__ qkv_b,
    unsigned short* __restrict__ Qh, unsigned short* __restrict__ Ql,
    unsigned short* __restrict__ Kh, unsigned short* __restrict__ Kl,
    unsigned short* __restrict__ Vt) {
  __shared__ unsigned short SM[16384];  // 32KB, carved; reused by V transpose
  unsigned short* Ah = SM;
  unsigned short* Al = SM + 4096;
  unsigned short* Bh = SM + 8192;
  unsigned short* Bl = SM + 12288;
  const int tid = threadIdx.x;
  const int lane = tid & 63, wid = tid >> 6;
  const int wm = wid >> 1, wn = wid & 1;
  const int bn = blockIdx.x, bm = blockIdx.y;
  const bool isV = (bn >= 16);
  const int quad = lane >> 4, c16 = lane & 15;
  const int ldrow = lane >> 2;
  const int ldk = (lane & 3) * 8;

  f4 acc[4][4];
#pragma unroll
  for (int a = 0; a < 4; ++a)
#pragma unroll
    for (int b = 0; b < 4; ++b) { f4 z = {0.f, 0.f, 0.f, 0.f}; acc[a][b] = z; }

  for (int kt = 0; kt < 32; ++kt) {
    const int k0 = kt * 32;
    __syncthreads();
#pragma unroll
    for (int r = 0; r < 2; ++r) {
      const int c = wid + r * 4;
      const int grow = c * 16 + ldrow;
      const size_t ao = (size_t)(bm * 128 + grow) * 1024 + k0 + ldk;
      const size_t bo = (size_t)(bn * 128 + grow) * 1024 + k0 + ldk;
      const int lo = c * 512 + lane * 8;
      gl2lds16(xh + ao, &Ah[lo]);
      gl2lds16(wh + bo, &Bh[lo]);
      if (!isV) {
        gl2lds16(xl + ao, &Al[lo]);
        gl2lds16(wl + bo, &Bl[lo]);
      }
    }
    __syncthreads();

    short8 ah[4], al[4], bhf[4], blf[4];
#pragma unroll
    for (int t = 0; t < 4; ++t) {
      ah[t] = *(const short8*)&Ah[(wm * 64 + t * 16 + c16) * 32 + quad * 8];
      bhf[t] = *(const short8*)&Bh[(wn * 64 + t * 16 + c16) * 32 + quad * 8];
      if (!isV) {
        al[t] = *(const short8*)&Al[(wm * 64 + t * 16 + c16) * 32 + quad * 8];
        blf[t] = *(const short8*)&Bl[(wn * 64 + t * 16 + c16) * 32 + quad * 8];
      }
    }
    if (isV) {
#pragma unroll
      for (int tm = 0; tm < 4; ++tm)
#pragma unroll
        for (int tn = 0; tn < 4; ++tn)
          acc[tm][tn] = __builtin_amdgcn_mfma_f32_16x16x32_bf16(ah[tm], bhf[tn], acc[tm][tn], 0, 0, 0);
    } else {
#pragma unroll
      for (int tm = 0; tm < 4; ++tm)
#pragma unroll
        for (int tn = 0; tn < 4; ++tn) {
          acc[tm][tn] = __builtin_amdgcn_mfma_f32_16x16x32_bf16(ah[tm], bhf[tn], acc[tm][tn], 0, 0, 0);
          acc[tm][tn] = __builtin_amdgcn_mfma_f32_16x16x32_bf16(ah[tm], blf[tn], acc[tm][tn], 0, 0, 0);
          acc[tm][tn] = __builtin_amdgcn_mfma_f32_16x16x32_bf16(al[tm], bhf[tn], acc[tm][tn], 0, 0, 0);
        }
    }
  }

  if (!isV) {
    // epilogue Q/K: hi/lo bf16 [bh][s][d]
#pragma unroll
    for (int tm = 0; tm < 4; ++tm) {
#pragma unroll
      for (int tn = 0; tn < 4; ++tn) {
        const int j = bn * 128 + wn * 64 + tn * 16 + c16;
        const float bias = qkv_b[j];
        const int which = j >> 10;
        const int rem = j & 1023;
        const int h = rem >> 6, d = rem & 63;
#pragma unroll
        for (int r = 0; r < 4; ++r) {
          const int i = bm * 128 + wm * 64 + tm * 16 + quad * 4 + r;
          const int b = i >> 11, s = i & 2047;
          const size_t off = (((size_t)(b * 16 + h)) * 2048 + (size_t)s) * 64 + d;
          const float v = acc[tm][tn][r] + bias;
          const unsigned short hi = bf16_rne(v);
          const unsigned short lo = bf16_rne(v - bf16_f32(hi));
          if (which == 0) { Qh[off] = hi; Ql[off] = lo; }
          else            { Kh[off] = hi; Kl[off] = lo; }
        }
      }
    }
  } else {
    // epilogue V: LDS transpose [d_local 128][s_local 128], then coalesced Vt
    __syncthreads();
#pragma unroll
    for (int tm = 0; tm < 4; ++tm) {
#pragma unroll
      for (int tn = 0; tn < 4; ++tn) {
        const int j = bn * 128 + wn * 64 + tn * 16 + c16;
        const float bias = qkv_b[j];
        const int d_local = wn * 64 + tn * 16 + c16;
#pragma unroll
        for (int r = 0; r < 4; ++r) {
          const int s_local = wm * 64 + tm * 16 + quad * 4 + r;
          SM[d_local * 128 + s_local] = bf16_rne(acc[tm][tn][r] + bias);
        }
      }
    }
    __syncthreads();
    const int b = (bm * 128) >> 11;
    const int s0 = (bm * 128) & 2047;   // per-batch s offset (bm*128 is global row)
    const int h2 = (bn - 16) * 2;
#pragma unroll
    for (int it = 0; it < 8; ++it) {
      const int chunk = it * 256 + tid;     // 2048 chunks of 8 ushorts
      const int dr = chunk >> 4;            // 0..127
      const int sc = (chunk & 15) * 8;
      const short8 v = *(const short8*)&SM[dr * 128 + sc];
      const int bh = b * 16 + h2 + (dr >> 6);
      const int d = dr & 63;
      *(short8*)&Vt[((size_t)bh * 64 + d) * 2048 + s0 + sc] = v;
    }
  }
}

// ---------------- kernel 2: MFMA flash attention + exact threefry sampling ----
// Round-2 restructure for OCCUPANCY: k_attn was ~50% stall-bound at ~29%
// occupancy (VALUBusy's gfx94x formula overstates 2x; true VALU ~43%).
// - 512-thread blocks (8 waves, q-tile 128): K/V LDS is q-independent, so
//   8 waves share the same 40KB that 4 shared before (LDS/wave halved).
// - grid k-split x2: sigmoid-Bernoulli attn has NO softmax normalization ->
//   O is a pure sum over k; two blocks each integrate half the k-range and
//   write bf16 partials (AO + ks*4194304). k_out combines them.
// - Pm stored as BYTES (0x40/0), expanded to 0x3F80 bf16 masks on read
//   (keeps LDS at exactly 40960B despite 128 q-rows).
// Phase order reverted to round-0 (threefry AFTER stage issue, proven best).
__global__ __launch_bounds__(512, 8) void k_attn(
    const unsigned short* __restrict__ Qh, const unsigned short* __restrict__ Ql,
    const unsigned short* __restrict__ Khg, const unsigned short* __restrict__ Klg,
    const unsigned short* __restrict__ Vtg, unsigned short* __restrict__ AO) {
  __shared__ unsigned short Ksh[4096], Ksl[4096], Vs[8192];
  __shared__ unsigned char Pmb[8192];
  const int tid = threadIdx.x;
  const int lane = tid & 63, w = tid >> 6;          // w 0..7
  const int quad = lane >> 4, c16 = lane & 15;
  const int q0 = blockIdx.x * 128;
  const int bh = blockIdx.y;
  const int ks = blockIdx.z;                        // k-split half (0/1)
  const int kbase = ks * 1024;
  const size_t base = (size_t)bh * (size_t)(2048 * 64);
  unsigned short* AOp = AO + (size_t)ks * 4194304u; // partial-O buffer

  // Q fragments for this wave's 16 rows (A-operand: m=c16, k=quad*8+j)
  const size_t qoff = base + (size_t)(q0 + w * 16 + c16) * 64 + quad * 8;
  const short8 qh0 = *(const short8*)&Qh[qoff];
  const short8 qh1 = *(const short8*)&Qh[qoff + 32];
  const short8 ql0 = *(const short8*)&Ql[qoff];
  const short8 ql1 = *(const short8*)&Ql[qoff + 32];

  // flat-index base for threefry: f = bh*2^22 + q*2048 + k
  const uint32_t fb = (uint32_t)bh * 4194304u +
                      (uint32_t)(q0 + w * 16 + quad * 4) * 2048u + (uint32_t)c16;

  // swizzled staging: 512 threads cover one 64x64 tile per buffer (1 chunk ea)
  const int r0 = tid >> 3, g0 = ((tid & 7) - r0) & 7;

  f4 oacc[4];
#pragma unroll
  for (int s = 0; s < 4; ++s) { f4 z = {0.f, 0.f, 0.f, 0.f}; oacc[s] = z; }

  auto stage = [&](int kb, int vbuf) {
    const size_t koff = base + (size_t)kb * 64;
    gl2lds16(Khg + koff + r0 * 64 + g0 * 8, &Ksh[tid * 8]);
    gl2lds16(Klg + koff + r0 * 64 + g0 * 8, &Ksl[tid * 8]);
    gl2lds16(Vtg + base + (size_t)r0 * 2048 + kb + g0 * 8, &Vs[vbuf * 4096 + tid * 8]);
  };

  stage(kbase, 0);

  for (int kt = 0; kt < 16; ++kt) {
    const int kb = kbase + kt * 64;
    const int vb = (kt & 1) * 4096;
    __syncthreads();  // tile kb staged; all waves past previous compute

    // S = Q.K^T split-bf16 3 passes; K fragments read inline (swizzled rows)
    f4 sacc[4];
#pragma unroll
    for (int sub = 0; sub < 4; ++sub) {
      const int rK = sub * 16 + c16;
      const int sA = ((quad + rK) & 7) * 8;
      const int sB = ((quad + 4 + rK) & 7) * 8;
      const short8 kh0 = *(const short8*)&Ksh[rK * 64 + sA];
      const short8 kh1 = *(const short8*)&Ksh[rK * 64 + sB];
      const short8 kl0 = *(const short8*)&Ksl[rK * 64 + sA];
      const short8 kl1 = *(const short8*)&Ksl[rK * 64 + sB];
      f4 s = {0.f, 0.f, 0.f, 0.f};
      s = __builtin_amdgcn_mfma_f32_16x16x32_bf16(qh0, kh0, s, 0, 0, 0);
      s = __builtin_amdgcn_mfma_f32_16x16x32_bf16(qh1, kh1, s, 0, 0, 0);
      s = __builtin_amdgcn_mfma_f32_16x16x32_bf16(qh0, kl0, s, 0, 0, 0);
      s = __builtin_amdgcn_mfma_f32_16x16x32_bf16(qh1, kl1, s, 0, 0, 0);
      s = __builtin_amdgcn_mfma_f32_16x16x32_bf16(ql0, kh0, s, 0, 0, 0);
      s = __builtin_amdgcn_mfma_f32_16x16x32_bf16(ql1, kh1, s, 0, 0, 0);
      sacc[sub] = s;
    }
    __syncthreads();  // K tile fully consumed by all waves (V[vb] untouched)
    if (kt < 15) stage(kb + 64, (kt & 1) ^ 1);  // lands during threefry below

    // threefry + sigmoid sample -> Pm bytes (0x40 / 0)
    // u < p  <=>  m*(1+e) < 2^23, m = (float)((o0^o1)>>9), e = 2^(s*-log2e/8)
#pragma unroll
    for (int sub = 0; sub < 4; ++sub) {
#pragma unroll
      for (int rr = 0; rr < 4; ++rr) {
        const uint32_t f = fb + (uint32_t)(rr * 2048) + (uint32_t)(kb + sub * 16);
        uint32_t o0, o1;
        threefry42(0u, f, o0, o1);
        const float m = (float)((o0 ^ o1) >> 9);
        const float e = __builtin_amdgcn_exp2f(sacc[sub][rr] * -0.18033688f);
        const int row = w * 16 + quad * 4 + rr;
        Pmb[row * 64 + sub * 16 + c16] = (fmaf(m, e, m) < 8388608.0f) ? 0x40u : 0u;
      }
    }

    // read own rows' bytes, expand to bf16 masks, PV
    // (rows are wave-private; same-wave ds ordering covers write->read)
    const int rp = w * 16 + c16;
    const uint32_t plo0 = *(const uint32_t*)&Pmb[rp * 64 + quad * 8];
    const uint32_t phi0 = *(const uint32_t*)&Pmb[rp * 64 + quad * 8 + 4];
    const uint32_t plo1 = *(const uint32_t*)&Pmb[rp * 64 + 32 + quad * 8];
    const uint32_t phi1 = *(const uint32_t*)&Pmb[rp * 64 + 32 + quad * 8 + 4];
    short8 pa0, pa1;
#pragma unroll
    for (int j = 0; j < 4; ++j) {
      pa0[j]     = (plo0 & (0x40u << (8 * j))) ? (short)0x3F80 : (short)0;
      pa0[j + 4] = (phi0 & (0x40u << (8 * j))) ? (short)0x3F80 : (short)0;
      pa1[j]     = (plo1 & (0x40u << (8 * j))) ? (short)0x3F80 : (short)0;
      pa1[j + 4] = (phi1 & (0x40u << (8 * j))) ? (short)0x3F80 : (short)0;
    }
#pragma unroll
    for (int sub = 0; sub < 4; ++sub) {
      const int rV = sub * 16 + c16;
      const short8 vv0 = *(const short8*)&Vs[vb + rV * 64 + ((quad + rV) & 7) * 8];
      const short8 vv1 = *(const short8*)&Vs[vb + rV * 64 + ((quad + 4 + rV) & 7) * 8];
      oacc[sub] = __builtin_amdgcn_mfma_f32_16x16x32_bf16(pa0, vv0, oacc[sub], 0, 0, 0);
      oacc[sub] = __builtin_amdgcn_mfma_f32_16x16x32_bf16(pa1, vv1, oacc[sub], 0, 0, 0);
    }
  }

  // epilogue: partial AO[b*2048+s][h*64+d] bf16; row=quad*4+r (q), col=c16 (d)
  const int b = bh >> 4, hh = bh & 15;
#pragma unroll
  for (int sub = 0; sub < 4; ++sub)
#pragma unroll
    for (int r = 0; r < 4; ++r) {
      const int srow = b * 2048 + q0 + w * 16 + quad * 4 + r;
      AOp[(size_t)srow * 1024 + hh * 64 + sub * 16 + c16] = bf16_rne(oacc[sub][r]);
    }
}

// ---------------- kernel 3: output projection, bf16 MFMA ----------------
// A-staging combines the two k-split partials (bf16 unpack-add-repack).
__global__ __launch_bounds__(256) void k_out(
    const unsigned short* __restrict__ A0, const unsigned short* __restrict__ A1,
    const unsigned short* __restrict__ Bw,
    const float* __restrict__ out_b, float* __restrict__ out) {
  __shared__ unsigned short As[128 * 32], Bs[128 * 32];
  const int tid = threadIdx.x;
  const int lane = tid & 63, wid = tid >> 6;
  const int wm = wid >> 1, wn = wid & 1;
  const int bn = blockIdx.x, bm = blockIdx.y;
  const int quad = lane >> 4, c16 = lane & 15;
  const int ldrow = lane >> 2;
  const int ldk = (lane & 3) * 8;

  f4 acc[4][4];
#pragma unroll
  for (int a = 0; a < 4; ++a)
#pragma unroll
    for (int b = 0; b < 4; ++b) { f4 z = {0.f, 0.f, 0.f, 0.f}; acc[a][b] = z; }

  for (int kt = 0; kt < 32; ++kt) {
    const int k0 = kt * 32;
    __syncthreads();
#pragma unroll
    for (int r = 0; r < 2; ++r) {
      const int c = wid + r * 4;
      const int grow = c * 16 + ldrow;
      const size_t ao = (size_t)(bm * 128 + grow) * 1024 + k0 + ldk;
      const size_t bo = (size_t)(bn * 128 + grow) * 1024 + k0 + ldk;
      const int lo = c * 512 + lane * 8;
      const short8 a0 = *(const short8*)&A0[ao];
      const short8 a1 = *(const short8*)&A1[ao];
      short8 acm;
#pragma unroll
      for (int j = 0; j < 8; ++j)
        acm[j] = (short)bf16_rne(bf16_f32((unsigned short)a0[j]) +
                                 bf16_f32((unsigned short)a1[j]));
      *(short8*)&As[lo] = acm;
      gl2lds16(Bw + bo, &Bs[lo]);
    }
    __syncthreads();

    short8 af[4], bf[4];
#pragma unroll
    for (int t = 0; t < 4; ++t) {
      af[t] = *(const short8*)&As[(wm * 64 + t * 16 + c16) * 32 + quad * 8];
      bf[t] = *(const short8*)&Bs[(wn * 64 + t * 16 + c16) * 32 + quad * 8];
    }
#pragma unroll
    for (int tm = 0; tm < 4; ++tm)
#pragma unroll
      for (int tn = 0; tn < 4; ++tn)
        acc[tm][tn] = __builtin_amdgcn_mfma_f32_16x16x32_bf16(af[tm], bf[tn], acc[tm][tn], 0, 0, 0);
  }

#pragma unroll
  for (int tm = 0; tm < 4; ++tm) {
#pragma unroll
    for (int tn = 0; tn < 4; ++tn) {
      const int j = bn * 128 + wn * 64 + tn * 16 + c16;
      const float bias = out_b[j];
#pragma unroll
      for (int r = 0; r < 4; ++r) {
        const int i = bm * 128 + wm * 64 + tm * 16 + quad * 4 + r;
        out[(size_t)i * 1024 + j] = acc[tm][tn][r] + bias;
      }
    }
  }
}

extern "C" void kernel_launch(void* const* d_in, const int* in_sizes, int n_in,
                              void* d_out, int out_size, void* d_ws, size_t ws_size,
                              hipStream_t stream) {
  const float* x     = (const float*)d_in[0];
  const float* qkv_w = (const float*)d_in[3];
  const float* qkv_b = (const float*)d_in[4];
  const float* out_w = (const float*)d_in[5];
  const float* out_b = (const float*)d_in[6];
  float* out = (float*)d_out;

  // workspace carve (ushorts); AO partials alias xh+xl (dead after k_qkv)
  unsigned short* xh  = (unsigned short*)d_ws;        // 4194304
  unsigned short* xl  = xh + 4194304;                 // 4194304
  unsigned short* wh  = xl + 4194304;                 // 3145728
  unsigned short* wl  = wh + 3145728;                 // 3145728
  unsigned short* woh = wl + 3145728;                 // 1048576
  unsigned short* Vt  = woh + 1048576;                // 4194304
  unsigned short* Qh  = Vt + 4194304;                 // 4194304
  unsigned short* Ql  = Qh + 4194304;                 // 4194304
  unsigned short* Kh  = Ql + 4194304;                 // 4194304
  unsigned short* Kl  = Kh + 4194304;                 // 4194304
  unsigned short* AO0 = xh;                           // alias (ks=0 partial)
  unsigned short* AO1 = xl;                           // alias (ks=1 partial)

  k_split<<<8192, 256, 0, stream>>>(x, qkv_w, out_w, xh, xl, wh, wl, woh);
  k_qkv<<<dim3(24, 32), 256, 0, stream>>>(xh, xl, wh, wl, qkv_b, Qh, Ql, Kh, Kl, Vt);
  k_attn<<<dim3(16, 32, 2), 512, 0, stream>>>(Qh, Ql, Kh, Kl, Vt, AO0);
  k_out<<<dim3(8, 32), 256, 0, stream>>>(AO0, AO1, woh, out_b, out);
}

// Round 4
// 539.645 us; speedup vs baseline: 1.0417x; 1.0417x over previous
//
#include <hip/hip_runtime.h>
#include <stdint.h>

// Problem constants
#define NB 2
#define NS 2048
#define NE 1024
#define NH 16
#define ND 64

typedef __attribute__((ext_vector_type(8))) short short8;
typedef __attribute__((ext_vector_type(4))) float f4;
typedef __attribute__((ext_vector_type(4))) unsigned short us4;

static __device__ __forceinline__ unsigned short bf16_rne(float x) {
  uint32_t u = __builtin_bit_cast(uint32_t, x);
  u += 0x7fffu + ((u >> 16) & 1u);
  return (unsigned short)(u >> 16);
}
static __device__ __forceinline__ float bf16_f32(unsigned short h) {
  uint32_t u = ((uint32_t)h) << 16;
  return __builtin_bit_cast(float, u);
}

// JAX threefry2x32, key = (0, 42), 20 rounds.
static __device__ __forceinline__ void threefry42(uint32_t x0, uint32_t x1,
                                                  uint32_t& o0, uint32_t& o1) {
  const uint32_t ks0 = 0u, ks1 = 42u;
  const uint32_t ks2 = 0u ^ 42u ^ 0x1BD11BDAu;
  x0 += ks0; x1 += ks1;
#define TF4(a,b,c,d) \
  x0 += x1; x1 = __builtin_rotateleft32(x1, a); x1 ^= x0; \
  x0 += x1; x1 = __builtin_rotateleft32(x1, b); x1 ^= x0; \
  x0 += x1; x1 = __builtin_rotateleft32(x1, c); x1 ^= x0; \
  x0 += x1; x1 = __builtin_rotateleft32(x1, d); x1 ^= x0;
  TF4(13,15,26,6)  x0 += ks1; x1 += ks2 + 1u;
  TF4(17,29,16,24) x0 += ks2; x1 += ks0 + 2u;
  TF4(13,15,26,6)  x0 += ks0; x1 += ks1 + 3u;
  TF4(17,29,16,24) x0 += ks1; x1 += ks2 + 4u;
  TF4(13,15,26,6)  x0 += ks2; x1 += ks0 + 5u;
#undef TF4
  o0 = x0; o1 = x1;
}

// async global->LDS 16B/lane.
static __device__ __forceinline__ void gl2lds16(const void* g, void* l) {
  __builtin_amdgcn_global_load_lds(
      (const __attribute__((address_space(1))) uint32_t*)g,
      (__attribute__((address_space(3))) uint32_t*)l, 16, 0, 0);
}

// ---------------- kernel 0: split fp32 -> bf16 hi/lo ----------------
__global__ void k_split(const float* __restrict__ x, const float* __restrict__ qw,
                        const float* __restrict__ ow,
                        unsigned short* __restrict__ xh, unsigned short* __restrict__ xl,
                        unsigned short* __restrict__ wh, unsigned short* __restrict__ wl,
                        unsigned short* __restrict__ woh) {
  for (uint32_t i = blockIdx.x * 256u + threadIdx.x; i < 8388608u; i += gridDim.x * 256u) {
    if (i < 4194304u) {
      float v = x[i];
      unsigned short hi = bf16_rne(v);
      xh[i] = hi;
      xl[i] = bf16_rne(v - bf16_f32(hi));
    } else if (i < 7340032u) {
      uint32_t j = i - 4194304u;
      float v = qw[j];
      unsigned short hi = bf16_rne(v);
      wh[j] = hi;
      wl[j] = bf16_rne(v - bf16_f32(hi));
    } else {
      uint32_t j = i - 7340032u;
      woh[j] = bf16_rne(ow[j]);
    }
  }
}

// ---------------- kernel 1: QKV GEMM, split-bf16 MFMA ----------------
// Q,K blocks (bn<16): 3-pass split-bf16, hi/lo outputs.
// V blocks (bn>=16): 1-pass bf16, epilogue LDS-transpose -> coalesced Vt stores.
__global__ __launch_bounds__(256) void k_qkv(
    const unsigned short* __restrict__ xh, const unsigned short* __restrict__ xl,
    const unsigned short* __restrict__ wh, const unsigned short* __restrict__ wl,
    const float* __restrict__ qkv_b,
    unsigned short* __restrict__ Qh, unsigned short* __restrict__ Ql,
    unsigned short* __restrict__ Kh, unsigned short* __restrict__ Kl,
    unsigned short* __restrict__ Vt) {
  __shared__ unsigned short SM[16384];  // 32KB, carved; reused by V transpose
  unsigned short* Ah = SM;
  unsigned short* Al = SM + 4096;
  unsigned short* Bh = SM + 8192;
  unsigned short* Bl = SM + 12288;
  const int tid = threadIdx.x;
  const int lane = tid & 63, wid = tid >> 6;
  const int wm = wid >> 1, wn = wid & 1;
  const int bn = blockIdx.x, bm = blockIdx.y;
  const bool isV = (bn >= 16);
  const int quad = lane >> 4, c16 = lane & 15;
  const int ldrow = lane >> 2;
  const int ldk = (lane & 3) * 8;

  f4 acc[4][4];
#pragma unroll
  for (int a = 0; a < 4; ++a)
#pragma unroll
    for (int b = 0; b < 4; ++b) { f4 z = {0.f, 0.f, 0.f, 0.f}; acc[a][b] = z; }

  for (int kt = 0; kt < 32; ++kt) {
    const int k0 = kt * 32;
    __syncthreads();
#pragma unroll
    for (int r = 0; r < 2; ++r) {
      const int c = wid + r * 4;
      const int grow = c * 16 + ldrow;
      const size_t ao = (size_t)(bm * 128 + grow) * 1024 + k0 + ldk;
      const size_t bo = (size_t)(bn * 128 + grow) * 1024 + k0 + ldk;
      const int lo = c * 512 + lane * 8;
      gl2lds16(xh + ao, &Ah[lo]);
      gl2lds16(wh + bo, &Bh[lo]);
      if (!isV) {
        gl2lds16(xl + ao, &Al[lo]);
        gl2lds16(wl + bo, &Bl[lo]);
      }
    }
    __syncthreads();

    short8 ah[4], al[4], bhf[4], blf[4];
#pragma unroll
    for (int t = 0; t < 4; ++t) {
      ah[t] = *(const short8*)&Ah[(wm * 64 + t * 16 + c16) * 32 + quad * 8];
      bhf[t] = *(const short8*)&Bh[(wn * 64 + t * 16 + c16) * 32 + quad * 8];
      if (!isV) {
        al[t] = *(const short8*)&Al[(wm * 64 + t * 16 + c16) * 32 + quad * 8];
        blf[t] = *(const short8*)&Bl[(wn * 64 + t * 16 + c16) * 32 + quad * 8];
      }
    }
    if (isV) {
#pragma unroll
      for (int tm = 0; tm < 4; ++tm)
#pragma unroll
        for (int tn = 0; tn < 4; ++tn)
          acc[tm][tn] = __builtin_amdgcn_mfma_f32_16x16x32_bf16(ah[tm], bhf[tn], acc[tm][tn], 0, 0, 0);
    } else {
#pragma unroll
      for (int tm = 0; tm < 4; ++tm)
#pragma unroll
        for (int tn = 0; tn < 4; ++tn) {
          acc[tm][tn] = __builtin_amdgcn_mfma_f32_16x16x32_bf16(ah[tm], bhf[tn], acc[tm][tn], 0, 0, 0);
          acc[tm][tn] = __builtin_amdgcn_mfma_f32_16x16x32_bf16(ah[tm], blf[tn], acc[tm][tn], 0, 0, 0);
          acc[tm][tn] = __builtin_amdgcn_mfma_f32_16x16x32_bf16(al[tm], bhf[tn], acc[tm][tn], 0, 0, 0);
        }
    }
  }

  if (!isV) {
    // epilogue Q/K: hi/lo bf16 [bh][s][d]
#pragma unroll
    for (int tm = 0; tm < 4; ++tm) {
#pragma unroll
      for (int tn = 0; tn < 4; ++tn) {
        const int j = bn * 128 + wn * 64 + tn * 16 + c16;
        const float bias = qkv_b[j];
        const int which = j >> 10;
        const int rem = j & 1023;
        const int h = rem >> 6, d = rem & 63;
#pragma unroll
        for (int r = 0; r < 4; ++r) {
          const int i = bm * 128 + wm * 64 + tm * 16 + quad * 4 + r;
          const int b = i >> 11, s = i & 2047;
          const size_t off = (((size_t)(b * 16 + h)) * 2048 + (size_t)s) * 64 + d;
          const float v = acc[tm][tn][r] + bias;
          const unsigned short hi = bf16_rne(v);
          const unsigned short lo = bf16_rne(v - bf16_f32(hi));
          if (which == 0) { Qh[off] = hi; Ql[off] = lo; }
          else            { Kh[off] = hi; Kl[off] = lo; }
        }
      }
    }
  } else {
    // epilogue V: LDS transpose [d_local 128][s_local 128], then coalesced Vt
    __syncthreads();
#pragma unroll
    for (int tm = 0; tm < 4; ++tm) {
#pragma unroll
      for (int tn = 0; tn < 4; ++tn) {
        const int j = bn * 128 + wn * 64 + tn * 16 + c16;
        const float bias = qkv_b[j];
        const int d_local = wn * 64 + tn * 16 + c16;
#pragma unroll
        for (int r = 0; r < 4; ++r) {
          const int s_local = wm * 64 + tm * 16 + quad * 4 + r;
          SM[d_local * 128 + s_local] = bf16_rne(acc[tm][tn][r] + bias);
        }
      }
    }
    __syncthreads();
    const int b = (bm * 128) >> 11;
    const int s0 = (bm * 128) & 2047;   // per-batch s offset (bm*128 is global row)
    const int h2 = (bn - 16) * 2;
#pragma unroll
    for (int it = 0; it < 8; ++it) {
      const int chunk = it * 256 + tid;     // 2048 chunks of 8 ushorts
      const int dr = chunk >> 4;            // 0..127
      const int sc = (chunk & 15) * 8;
      const short8 v = *(const short8*)&SM[dr * 128 + sc];
      const int bh = b * 16 + h2 + (dr >> 6);
      const int d = dr & 63;
      *(short8*)&Vt[((size_t)bh * 64 + d) * 2048 + s0 + sc] = v;
    }
  }
}

// ---------------- kernel 2: MFMA flash attention + exact threefry sampling ----
// Round-4 == round-3 kernel resubmitted (R3 bench was an infrastructure
// failure: "MI355X container failed twice"; no counters, no verification).
// Round-0 structure (proven 324us, no spills, 0 conflicts) with an LDS diet +
// more blocks to raise occupancy WITHOUT a VGPR cap (R2 lesson):
// - Pm LDS buffer ELIMINATED: each lane packs its 16 Bernoulli bits into a
//   uint32 (bit = sub*4+rr); the S->PV layout transpose is 8 ds_bpermute_b32
//   (crossbar, no bank conflicts) + bit extracts. Saves 8KB LDS and all Pm
//   ds_write/ds_read traffic.
// - LDS now 32KB (Ksh 8 + Ksl 8 + Vs dbuf 16) -> 5 blocks/CU.
// - grid k-split x2 (z dim): no softmax normalization, O is a pure k-sum;
//   halves write bf16 partials (AO0/AO1 aliases), k_out combines (R2-verified).
//   2048 blocks -> 5 resident blocks/CU = 20 waves/CU (~62%) vs ~29%.
// - NO launch_bounds min-wave arg (R2's spill disaster); compiler-free VGPR.
__global__ __launch_bounds__(256) void k_attn(
    const unsigned short* __restrict__ Qh, const unsigned short* __restrict__ Ql,
    const unsigned short* __restrict__ Khg, const unsigned short* __restrict__ Klg,
    const unsigned short* __restrict__ Vtg, unsigned short* __restrict__ AO) {
  __shared__ unsigned short Ksh[4096], Ksl[4096], Vs[8192];
  const int tid = threadIdx.x;
  const int lane = tid & 63, w = tid >> 6;
  const int quad = lane >> 4, c16 = lane & 15;
  const int q0 = blockIdx.x * 64;
  const int bh = blockIdx.y;
  const int ks = blockIdx.z;                        // k-split half (0/1)
  const int kbase = ks * 1024;
  const size_t base = (size_t)bh * (size_t)(2048 * 64);
  unsigned short* AOp = AO + (size_t)ks * 4194304u; // partial-O buffer

  // Q fragments for this wave's 16 rows (A-operand: m=c16, k=quad*8+j)
  const size_t qoff = base + (size_t)(q0 + w * 16 + c16) * 64 + quad * 8;
  const short8 qh0 = *(const short8*)&Qh[qoff];
  const short8 qh1 = *(const short8*)&Qh[qoff + 32];
  const short8 ql0 = *(const short8*)&Ql[qoff];
  const short8 ql1 = *(const short8*)&Ql[qoff + 32];

  // flat-index base for threefry: f = bh*2^22 + q*2048 + k
  const uint32_t fb = (uint32_t)bh * 4194304u +
                      (uint32_t)(q0 + w * 16 + quad * 4) * 2048u + (uint32_t)c16;

  // swizzled staging indices: LDS chunk c holds global chunk ((c&7) - (c>>3)) & 7
  const int c0 = tid, r0 = c0 >> 3, g0 = ((c0 & 7) - r0) & 7;
  const int c1 = tid + 256, r1 = c1 >> 3, g1 = ((c1 & 7) - r1) & 7;

  // bpermute transpose constants: P(q = w*16+c16, k = quad*8+j [+32]) comes
  // from lane (c16>>2)*16 + (quad&1)*8 + j, bit (quad>>1)*4 + (c16&3) [+8]
  const int lsb = (((c16 >> 2) << 4) + ((quad & 1) << 3)) << 2;
  const int bitsel = ((quad >> 1) << 2) + (c16 & 3);

  f4 oacc[4];
#pragma unroll
  for (int s = 0; s < 4; ++s) { f4 z = {0.f, 0.f, 0.f, 0.f}; oacc[s] = z; }

  auto stage = [&](int kb, int vbuf) {
    const size_t koff = base + (size_t)kb * 64;
    gl2lds16(Khg + koff + r0 * 64 + g0 * 8, &Ksh[c0 * 8]);
    gl2lds16(Klg + koff + r0 * 64 + g0 * 8, &Ksl[c0 * 8]);
    gl2lds16(Vtg + base + (size_t)r0 * 2048 + kb + g0 * 8, &Vs[vbuf * 4096 + c0 * 8]);
    gl2lds16(Khg + koff + r1 * 64 + g1 * 8, &Ksh[c1 * 8]);
    gl2lds16(Klg + koff + r1 * 64 + g1 * 8, &Ksl[c1 * 8]);
    gl2lds16(Vtg + base + (size_t)r1 * 2048 + kb + g1 * 8, &Vs[vbuf * 4096 + c1 * 8]);
  };

  stage(kbase, 0);

  for (int kt = 0; kt < 16; ++kt) {
    const int kb = kbase + kt * 64;
    const int vb = (kt & 1) * 4096;
    __syncthreads();  // tile kb staged; all waves past previous compute

    // S = Q.K^T split-bf16 3 passes; K fragments read inline (swizzled rows)
    f4 sacc[4];
#pragma unroll
    for (int sub = 0; sub < 4; ++sub) {
      const int rK = sub * 16 + c16;
      const int sA = ((quad + rK) & 7) * 8;
      const int sB = ((quad + 4 + rK) & 7) * 8;
      const short8 kh0 = *(const short8*)&Ksh[rK * 64 + sA];
      const short8 kh1 = *(const short8*)&Ksh[rK * 64 + sB];
      const short8 kl0 = *(const short8*)&Ksl[rK * 64 + sA];
      const short8 kl1 = *(const short8*)&Ksl[rK * 64 + sB];
      f4 s = {0.f, 0.f, 0.f, 0.f};
      s = __builtin_amdgcn_mfma_f32_16x16x32_bf16(qh0, kh0, s, 0, 0, 0);
      s = __builtin_amdgcn_mfma_f32_16x16x32_bf16(qh1, kh1, s, 0, 0, 0);
      s = __builtin_amdgcn_mfma_f32_16x16x32_bf16(qh0, kl0, s, 0, 0, 0);
      s = __builtin_amdgcn_mfma_f32_16x16x32_bf16(qh1, kl1, s, 0, 0, 0);
      s = __builtin_amdgcn_mfma_f32_16x16x32_bf16(ql0, kh0, s, 0, 0, 0);
      s = __builtin_amdgcn_mfma_f32_16x16x32_bf16(ql1, kh1, s, 0, 0, 0);
      sacc[sub] = s;
    }
    __syncthreads();  // K tile fully consumed by all waves (V[vb] untouched)
    if (kt < 15) stage(kb + 64, (kt & 1) ^ 1);  // lands during threefry below

    // threefry + sigmoid sample -> packed per-lane bits (bit = sub*4+rr)
    // u < p  <=>  m*(1+e) < 2^23, m = (float)((o0^o1)>>9), e = 2^(s*-log2e/8)
    uint32_t pk = 0u;
#pragma unroll
    for (int sub = 0; sub < 4; ++sub) {
#pragma unroll
      for (int rr = 0; rr < 4; ++rr) {
        const uint32_t f = fb + (uint32_t)(rr * 2048) + (uint32_t)(kb + sub * 16);
        uint32_t o0, o1;
        threefry42(0u, f, o0, o1);
        const float m = (float)((o0 ^ o1) >> 9);
        const float e = __builtin_amdgcn_exp2f(sacc[sub][rr] * -0.18033688f);
        if (fmaf(m, e, m) < 8388608.0f) pk |= (1u << (sub * 4 + rr));
      }
    }

    // in-register S->PV transpose via bpermute, then PV MFMAs
    short8 pa0, pa1;
#pragma unroll
    for (int j = 0; j < 8; ++j) {
      const uint32_t t =
          ((uint32_t)__builtin_amdgcn_ds_bpermute(lsb + j * 4, (int)pk)) >> bitsel;
      pa0[j] = (t & 1u) ? (short)0x3F80 : (short)0;
      pa1[j] = (t & 256u) ? (short)0x3F80 : (short)0;
    }
#pragma unroll
    for (int sub = 0; sub < 4; ++sub) {
      const int rV = sub * 16 + c16;
      const short8 vv0 = *(const short8*)&Vs[vb + rV * 64 + ((quad + rV) & 7) * 8];
      const short8 vv1 = *(const short8*)&Vs[vb + rV * 64 + ((quad + 4 + rV) & 7) * 8];
      oacc[sub] = __builtin_amdgcn_mfma_f32_16x16x32_bf16(pa0, vv0, oacc[sub], 0, 0, 0);
      oacc[sub] = __builtin_amdgcn_mfma_f32_16x16x32_bf16(pa1, vv1, oacc[sub], 0, 0, 0);
    }
  }

  // epilogue: partial AO[b*2048+s][h*64+d] bf16; row=quad*4+r (q), col=c16 (d)
  const int b = bh >> 4, hh = bh & 15;
#pragma unroll
  for (int sub = 0; sub < 4; ++sub)
#pragma unroll
    for (int r = 0; r < 4; ++r) {
      const int srow = b * 2048 + q0 + w * 16 + quad * 4 + r;
      AOp[(size_t)srow * 1024 + hh * 64 + sub * 16 + c16] = bf16_rne(oacc[sub][r]);
    }
}

// ---------------- kernel 3: output projection, bf16 MFMA ----------------
// A-staging combines the two k-split partials (bf16 unpack-add-repack).
__global__ __launch_bounds__(256) void k_out(
    const unsigned short* __restrict__ A0, const unsigned short* __restrict__ A1,
    const unsigned short* __restrict__ Bw,
    const float* __restrict__ out_b, float* __restrict__ out) {
  __shared__ unsigned short As[128 * 32], Bs[128 * 32];
  const int tid = threadIdx.x;
  const int lane = tid & 63, wid = tid >> 6;
  const int wm = wid >> 1, wn = wid & 1;
  const int bn = blockIdx.x, bm = blockIdx.y;
  const int quad = lane >> 4, c16 = lane & 15;
  const int ldrow = lane >> 2;
  const int ldk = (lane & 3) * 8;

  f4 acc[4][4];
#pragma unroll
  for (int a = 0; a < 4; ++a)
#pragma unroll
    for (int b = 0; b < 4; ++b) { f4 z = {0.f, 0.f, 0.f, 0.f}; acc[a][b] = z; }

  for (int kt = 0; kt < 32; ++kt) {
    const int k0 = kt * 32;
    __syncthreads();
#pragma unroll
    for (int r = 0; r < 2; ++r) {
      const int c = wid + r * 4;
      const int grow = c * 16 + ldrow;
      const size_t ao = (size_t)(bm * 128 + grow) * 1024 + k0 + ldk;
      const size_t bo = (size_t)(bn * 128 + grow) * 1024 + k0 + ldk;
      const int lo = c * 512 + lane * 8;
      const short8 a0 = *(const short8*)&A0[ao];
      const short8 a1 = *(const short8*)&A1[ao];
      short8 acm;
#pragma unroll
      for (int j = 0; j < 8; ++j)
        acm[j] = (short)bf16_rne(bf16_f32((unsigned short)a0[j]) +
                                 bf16_f32((unsigned short)a1[j]));
      *(short8*)&As[lo] = acm;
      gl2lds16(Bw + bo, &Bs[lo]);
    }
    __syncthreads();

    short8 af[4], bf[4];
#pragma unroll
    for (int t = 0; t < 4; ++t) {
      af[t] = *(const short8*)&As[(wm * 64 + t * 16 + c16) * 32 + quad * 8];
      bf[t] = *(const short8*)&Bs[(wn * 64 + t * 16 + c16) * 32 + quad * 8];
    }
#pragma unroll
    for (int tm = 0; tm < 4; ++tm)
#pragma unroll
      for (int tn = 0; tn < 4; ++tn)
        acc[tm][tn] = __builtin_amdgcn_mfma_f32_16x16x32_bf16(af[tm], bf[tn], acc[tm][tn], 0, 0, 0);
  }

#pragma unroll
  for (int tm = 0; tm < 4; ++tm) {
#pragma unroll
    for (int tn = 0; tn < 4; ++tn) {
      const int j = bn * 128 + wn * 64 + tn * 16 + c16;
      const float bias = out_b[j];
#pragma unroll
      for (int r = 0; r < 4; ++r) {
        const int i = bm * 128 + wm * 64 + tm * 16 + quad * 4 + r;
        out[(size_t)i * 1024 + j] = acc[tm][tn][r] + bias;
      }
    }
  }
}

extern "C" void kernel_launch(void* const* d_in, const int* in_sizes, int n_in,
                              void* d_out, int out_size, void* d_ws, size_t ws_size,
                              hipStream_t stream) {
  const float* x     = (const float*)d_in[0];
  const float* qkv_w = (const float*)d_in[3];
  const float* qkv_b = (const float*)d_in[4];
  const float* out_w = (const float*)d_in[5];
  const float* out_b = (const float*)d_in[6];
  float* out = (float*)d_out;

  // workspace carve (ushorts); AO partials alias xh+xl (dead after k_qkv)
  unsigned short* xh  = (unsigned short*)d_ws;        // 4194304
  unsigned short* xl  = xh + 4194304;                 // 4194304
  unsigned short* wh  = xl + 4194304;                 // 3145728
  unsigned short* wl  = wh + 3145728;                 // 3145728
  unsigned short* woh = wl + 3145728;                 // 1048576
  unsigned short* Vt  = woh + 1048576;                // 4194304
  unsigned short* Qh  = Vt + 4194304;                 // 4194304
  unsigned short* Ql  = Qh + 4194304;                 // 4194304
  unsigned short* Kh  = Ql + 4194304;                 // 4194304
  unsigned short* Kl  = Kh + 4194304;                 // 4194304
  unsigned short* AO0 = xh;                           // alias (ks=0 partial)
  unsigned short* AO1 = xl;                           // alias (ks=1 partial)

  k_split<<<8192, 256, 0, stream>>>(x, qkv_w, out_w, xh, xl, wh, wl, woh);
  k_qkv<<<dim3(24, 32), 256, 0, stream>>>(xh, xl, wh, wl, qkv_b, Qh, Ql, Kh, Kl, Vt);
  k_attn<<<dim3(32, 32, 2), 256, 0, stream>>>(Qh, Ql, Kh, Kl, Vt, AO0);
  k_out<<<dim3(8, 32), 256, 0, stream>>>(AO0, AO1, woh, out_b, out);
}

// Round 5
// 536.322 us; speedup vs baseline: 1.0481x; 1.0062x over previous
//
#include <hip/hip_runtime.h>
#include <stdint.h>

// Problem constants
#define NB 2
#define NS 2048
#define NE 1024
#define NH 16
#define ND 64

typedef __attribute__((ext_vector_type(8))) short short8;
typedef __attribute__((ext_vector_type(4))) float f4;
typedef __attribute__((ext_vector_type(16))) float f16v;
typedef __attribute__((ext_vector_type(4))) unsigned short us4;

static __device__ __forceinline__ unsigned short bf16_rne(float x) {
  uint32_t u = __builtin_bit_cast(uint32_t, x);
  u += 0x7fffu + ((u >> 16) & 1u);
  return (unsigned short)(u >> 16);
}
static __device__ __forceinline__ float bf16_f32(unsigned short h) {
  uint32_t u = ((uint32_t)h) << 16;
  return __builtin_bit_cast(float, u);
}

// JAX threefry2x32, key = (0, 42), 20 rounds.
static __device__ __forceinline__ void threefry42(uint32_t x0, uint32_t x1,
                                                  uint32_t& o0, uint32_t& o1) {
  const uint32_t ks0 = 0u, ks1 = 42u;
  const uint32_t ks2 = 0u ^ 42u ^ 0x1BD11BDAu;
  x0 += ks0; x1 += ks1;
#define TF4(a,b,c,d) \
  x0 += x1; x1 = __builtin_rotateleft32(x1, a); x1 ^= x0; \
  x0 += x1; x1 = __builtin_rotateleft32(x1, b); x1 ^= x0; \
  x0 += x1; x1 = __builtin_rotateleft32(x1, c); x1 ^= x0; \
  x0 += x1; x1 = __builtin_rotateleft32(x1, d); x1 ^= x0;
  TF4(13,15,26,6)  x0 += ks1; x1 += ks2 + 1u;
  TF4(17,29,16,24) x0 += ks2; x1 += ks0 + 2u;
  TF4(13,15,26,6)  x0 += ks0; x1 += ks1 + 3u;
  TF4(17,29,16,24) x0 += ks1; x1 += ks2 + 4u;
  TF4(13,15,26,6)  x0 += ks2; x1 += ks0 + 5u;
#undef TF4
  o0 = x0; o1 = x1;
}

// async global->LDS 16B/lane.
static __device__ __forceinline__ void gl2lds16(const void* g, void* l) {
  __builtin_amdgcn_global_load_lds(
      (const __attribute__((address_space(1))) uint32_t*)g,
      (__attribute__((address_space(3))) uint32_t*)l, 16, 0, 0);
}

// ---------------- kernel 0: split fp32 -> bf16 hi/lo ----------------
__global__ void k_split(const float* __restrict__ x, const float* __restrict__ qw,
                        const float* __restrict__ ow,
                        unsigned short* __restrict__ xh, unsigned short* __restrict__ xl,
                        unsigned short* __restrict__ wh, unsigned short* __restrict__ wl,
                        unsigned short* __restrict__ woh) {
  for (uint32_t i = blockIdx.x * 256u + threadIdx.x; i < 8388608u; i += gridDim.x * 256u) {
    if (i < 4194304u) {
      float v = x[i];
      unsigned short hi = bf16_rne(v);
      xh[i] = hi;
      xl[i] = bf16_rne(v - bf16_f32(hi));
    } else if (i < 7340032u) {
      uint32_t j = i - 4194304u;
      float v = qw[j];
      unsigned short hi = bf16_rne(v);
      wh[j] = hi;
      wl[j] = bf16_rne(v - bf16_f32(hi));
    } else {
      uint32_t j = i - 7340032u;
      woh[j] = bf16_rne(ow[j]);
    }
  }
}

// ---------------- kernel 1: QKV GEMM, split-bf16 MFMA ----------------
__global__ __launch_bounds__(256) void k_qkv(
    const unsigned short* __restrict__ xh, const unsigned short* __restrict__ xl,
    const unsigned short* __restrict__ wh, const unsigned short* __restrict__ wl,
    const float* __restrict__ qkv_b,
    unsigned short* __restrict__ Qh, unsigned short* __restrict__ Ql,
    unsigned short* __restrict__ Kh, unsigned short* __restrict__ Kl,
    unsigned short* __restrict__ Vt) {
  __shared__ unsigned short SM[16384];  // 32KB, carved; reused by V transpose
  unsigned short* Ah = SM;
  unsigned short* Al = SM + 4096;
  unsigned short* Bh = SM + 8192;
  unsigned short* Bl = SM + 12288;
  const int tid = threadIdx.x;
  const int lane = tid & 63, wid = tid >> 6;
  const int wm = wid >> 1, wn = wid & 1;
  const int bn = blockIdx.x, bm = blockIdx.y;
  const bool isV = (bn >= 16);
  const int quad = lane >> 4, c16 = lane & 15;
  const int ldrow = lane >> 2;
  const int ldk = (lane & 3) * 8;

  f4 acc[4][4];
#pragma unroll
  for (int a = 0; a < 4; ++a)
#pragma unroll
    for (int b = 0; b < 4; ++b) { f4 z = {0.f, 0.f, 0.f, 0.f}; acc[a][b] = z; }

  for (int kt = 0; kt < 32; ++kt) {
    const int k0 = kt * 32;
    __syncthreads();
#pragma unroll
    for (int r = 0; r < 2; ++r) {
      const int c = wid + r * 4;
      const int grow = c * 16 + ldrow;
      const size_t ao = (size_t)(bm * 128 + grow) * 1024 + k0 + ldk;
      const size_t bo = (size_t)(bn * 128 + grow) * 1024 + k0 + ldk;
      const int lo = c * 512 + lane * 8;
      gl2lds16(xh + ao, &Ah[lo]);
      gl2lds16(wh + bo, &Bh[lo]);
      if (!isV) {
        gl2lds16(xl + ao, &Al[lo]);
        gl2lds16(wl + bo, &Bl[lo]);
      }
    }
    __syncthreads();

    short8 ah[4], al[4], bhf[4], blf[4];
#pragma unroll
    for (int t = 0; t < 4; ++t) {
      ah[t] = *(const short8*)&Ah[(wm * 64 + t * 16 + c16) * 32 + quad * 8];
      bhf[t] = *(const short8*)&Bh[(wn * 64 + t * 16 + c16) * 32 + quad * 8];
      if (!isV) {
        al[t] = *(const short8*)&Al[(wm * 64 + t * 16 + c16) * 32 + quad * 8];
        blf[t] = *(const short8*)&Bl[(wn * 64 + t * 16 + c16) * 32 + quad * 8];
      }
    }
    if (isV) {
#pragma unroll
      for (int tm = 0; tm < 4; ++tm)
#pragma unroll
        for (int tn = 0; tn < 4; ++tn)
          acc[tm][tn] = __builtin_amdgcn_mfma_f32_16x16x32_bf16(ah[tm], bhf[tn], acc[tm][tn], 0, 0, 0);
    } else {
#pragma unroll
      for (int tm = 0; tm < 4; ++tm)
#pragma unroll
        for (int tn = 0; tn < 4; ++tn) {
          acc[tm][tn] = __builtin_amdgcn_mfma_f32_16x16x32_bf16(ah[tm], bhf[tn], acc[tm][tn], 0, 0, 0);
          acc[tm][tn] = __builtin_amdgcn_mfma_f32_16x16x32_bf16(ah[tm], blf[tn], acc[tm][tn], 0, 0, 0);
          acc[tm][tn] = __builtin_amdgcn_mfma_f32_16x16x32_bf16(al[tm], bhf[tn], acc[tm][tn], 0, 0, 0);
        }
    }
  }

  if (!isV) {
#pragma unroll
    for (int tm = 0; tm < 4; ++tm) {
#pragma unroll
      for (int tn = 0; tn < 4; ++tn) {
        const int j = bn * 128 + wn * 64 + tn * 16 + c16;
        const float bias = qkv_b[j];
        const int which = j >> 10;
        const int rem = j & 1023;
        const int h = rem >> 6, d = rem & 63;
#pragma unroll
        for (int r = 0; r < 4; ++r) {
          const int i = bm * 128 + wm * 64 + tm * 16 + quad * 4 + r;
          const int b = i >> 11, s = i & 2047;
          const size_t off = (((size_t)(b * 16 + h)) * 2048 + (size_t)s) * 64 + d;
          const float v = acc[tm][tn][r] + bias;
          const unsigned short hi = bf16_rne(v);
          const unsigned short lo = bf16_rne(v - bf16_f32(hi));
          if (which == 0) { Qh[off] = hi; Ql[off] = lo; }
          else            { Kh[off] = hi; Kl[off] = lo; }
        }
      }
    }
  } else {
    __syncthreads();
#pragma unroll
    for (int tm = 0; tm < 4; ++tm) {
#pragma unroll
      for (int tn = 0; tn < 4; ++tn) {
        const int j = bn * 128 + wn * 64 + tn * 16 + c16;
        const float bias = qkv_b[j];
        const int d_local = wn * 64 + tn * 16 + c16;
#pragma unroll
        for (int r = 0; r < 4; ++r) {
          const int s_local = wm * 64 + tm * 16 + quad * 4 + r;
          SM[d_local * 128 + s_local] = bf16_rne(acc[tm][tn][r] + bias);
        }
      }
    }
    __syncthreads();
    const int b = (bm * 128) >> 11;
    const int s0 = (bm * 128) & 2047;
    const int h2 = (bn - 16) * 2;
#pragma unroll
    for (int it = 0; it < 8; ++it) {
      const int chunk = it * 256 + tid;
      const int dr = chunk >> 4;
      const int sc = (chunk & 15) * 8;
      const short8 v = *(const short8*)&SM[dr * 128 + sc];
      const int bh = b * 16 + h2 + (dr >> 6);
      const int d = dr & 63;
      *(short8*)&Vt[((size_t)bh * 64 + d) * 2048 + s0 + sc] = v;
    }
  }
}

// ---------------- kernel 2: MFMA flash attention + exact threefry sampling ----
// Round-5: LDS-PIPE DIET. R0/R2/R4 all pin real VALU duty at ~42-45% across
// occupancy 29/62/37% -> shared-resource bound; arithmetic says the CU LDS pipe
// was ~86% busy (38 LDS ops/wave/kt). Fix: 32x32x16 MFMAs (2x MAC per LDS byte)
// + swapped S-compute (S^T = K.Q^T, K as LDS A-operand, Q in regs as B).
// C-layout col=lane&31 => each lane holds ONE q-col and 32 k-samples => P is
// lane-local for PV (B-operand bits from own pk + one ds_bpermute half-swap).
// PV: A = Vt[d][k] from LDS, B = P bits, C = O^T (col=q). Per wave per kt:
// 2048 samples (32q x 64k) with 16KB K + 8KB V + 2 bpermute => 2.1x less LDS
// traffic per sample. Threefry f = bh*2^22 + q*2048 + k preserved bit-exact.
__global__ __launch_bounds__(256) void k_attn(
    const unsigned short* __restrict__ Qh, const unsigned short* __restrict__ Ql,
    const unsigned short* __restrict__ Khg, const unsigned short* __restrict__ Klg,
    const unsigned short* __restrict__ Vtg, unsigned short* __restrict__ AO) {
  __shared__ unsigned short Ksh[4096], Ksl[4096], Vs[8192];
  const int tid = threadIdx.x;
  const int lane = tid & 63, w = tid >> 6;
  const int l31 = lane & 31, h = lane >> 5;
  const int q0 = blockIdx.x * 128;
  const int bh = blockIdx.y;
  const int ks = blockIdx.z;                        // k-split half (0/1)
  const int kbase = ks * 1024;
  const size_t base = (size_t)bh * (size_t)(2048 * 64);
  unsigned short* AOp = AO + (size_t)ks * 4194304u; // partial-O buffer
  const int q_lane = q0 + w * 32 + l31;             // this lane's q row

  // Q B-fragments (col=q=l31, k-dim=d): element j of frag ds -> d = ds*16+h*8+j
  const size_t qoff = base + (size_t)q_lane * 64 + h * 8;
  short8 qhf[4], qlf[4];
#pragma unroll
  for (int ds = 0; ds < 4; ++ds) {
    qhf[ds] = *(const short8*)&Qh[qoff + ds * 16];
    qlf[ds] = *(const short8*)&Ql[qoff + ds * 16];
  }

  // threefry flat base: f = bh*2^22 + q*2048 + k; this lane's k-rows are
  // km*32 + (rg&3) + 8*(rg>>2) + 4*h  (S^T C-layout row mapping)
  const uint32_t Fq = (uint32_t)bh * 4194304u + (uint32_t)q_lane * 2048u + 4u * (uint32_t)h;

  // swizzled staging indices (R0-proven): LDS chunk c holds global chunk of
  // row r=c>>3 rotated by r; reads use ((chunk + row)&7).
  const int c0 = tid, r0 = c0 >> 3, g0 = ((c0 & 7) - r0) & 7;
  const int c1 = tid + 256, r1 = c1 >> 3, g1 = ((c1 & 7) - r1) & 7;
  const int swidx = (lane ^ 32) << 2;               // bpermute half-swap index

  auto stage = [&](int kb, int vbuf) {
    const size_t koff = base + (size_t)kb * 64;
    gl2lds16(Khg + koff + r0 * 64 + g0 * 8, &Ksh[c0 * 8]);
    gl2lds16(Klg + koff + r0 * 64 + g0 * 8, &Ksl[c0 * 8]);
    gl2lds16(Vtg + base + (size_t)r0 * 2048 + kb + g0 * 8, &Vs[vbuf * 4096 + c0 * 8]);
    gl2lds16(Khg + koff + r1 * 64 + g1 * 8, &Ksh[c1 * 8]);
    gl2lds16(Klg + koff + r1 * 64 + g1 * 8, &Ksl[c1 * 8]);
    gl2lds16(Vtg + base + (size_t)r1 * 2048 + kb + g1 * 8, &Vs[vbuf * 4096 + c1 * 8]);
  };

  f16v oacc0 = {0.f,0.f,0.f,0.f,0.f,0.f,0.f,0.f,0.f,0.f,0.f,0.f,0.f,0.f,0.f,0.f};
  f16v oacc1 = oacc0;

  stage(kbase, 0);

  // threefry+sample for one 16-reg S^T accumulator -> 16-bit mask
  auto sample16 = [&](const f16v& s, uint32_t F) -> uint32_t {
    uint32_t pk = 0u;
#pragma unroll
    for (int rg = 0; rg < 16; ++rg) {
      uint32_t o0, o1;
      threefry42(0u, F + (uint32_t)((rg & 3) + 8 * (rg >> 2)), o0, o1);
      const float m = (float)((o0 ^ o1) >> 9);
      const float e = __builtin_amdgcn_exp2f(s[rg] * -0.18033688f);
      if (fmaf(m, e, m) < 8388608.0f) pk |= (1u << rg);
    }
    return pk;
  };

  // PV for one k-mtile: bits -> B-frags -> 4 MFMAs (2 ksteps x 2 d-mtiles)
  auto pv16 = [&](uint32_t pk, int km, int vb) {
    const uint32_t pksw = (uint32_t)__builtin_amdgcn_ds_bpermute(swidx, (int)pk);
    const uint32_t ph0 = h ? pksw : pk;   // bits held by lane-half 0 (rows r%8<4)
    const uint32_t ph1 = h ? pk : pksw;   // bits held by lane-half 1
#pragma unroll
    for (int k2 = 0; k2 < 2; ++k2) {
      const int bb = (k2 * 2 + h) * 4;    // nibble base: blk = 2*ks' + h_cons
      const uint32_t nl = (ph0 >> bb) & 15u;
      const uint32_t nh = (ph1 >> bb) & 15u;
      short8 pf;
#pragma unroll
      for (int j = 0; j < 4; ++j) {
        pf[j]     = (nl & (1u << j)) ? (short)0x3F80 : (short)0;
        pf[j + 4] = (nh & (1u << j)) ? (short)0x3F80 : (short)0;
      }
      const int vch = (km * 2 + k2) * 2 + h;  // V k-chunk for this frag
#pragma unroll
      for (int dm = 0; dm < 2; ++dm) {
        const int vrow = dm * 32 + l31;
        const short8 vf = *(const short8*)&Vs[vb + vrow * 64 + ((vch + vrow) & 7) * 8];
        if (dm == 0) oacc0 = __builtin_amdgcn_mfma_f32_32x32x16_bf16(vf, pf, oacc0, 0, 0, 0);
        else         oacc1 = __builtin_amdgcn_mfma_f32_32x32x16_bf16(vf, pf, oacc1, 0, 0, 0);
      }
    }
  };

  for (int kt = 0; kt < 16; ++kt) {
    const int kb = kbase + kt * 64;
    const int vb = (kt & 1) * 4096;
    __syncthreads();  // tile kb staged; all waves past previous compute

    // S^T = K.Q^T, split-bf16 3 passes, both k-mtiles (24 MFMAs, 16KB K reads)
    f16v s0 = {0.f,0.f,0.f,0.f,0.f,0.f,0.f,0.f,0.f,0.f,0.f,0.f,0.f,0.f,0.f,0.f};
    f16v s1 = s0;
    {
      const int krow0 = l31, krow1 = 32 + l31;
#pragma unroll
      for (int ds = 0; ds < 4; ++ds) {
        const int ch = ds * 2 + h;
        const int off0 = krow0 * 64 + ((ch + krow0) & 7) * 8;
        const int off1 = krow1 * 64 + ((ch + krow1) & 7) * 8;
        const short8 kh0 = *(const short8*)&Ksh[off0];
        const short8 kl0 = *(const short8*)&Ksl[off0];
        const short8 kh1 = *(const short8*)&Ksh[off1];
        const short8 kl1 = *(const short8*)&Ksl[off1];
        s0 = __builtin_amdgcn_mfma_f32_32x32x16_bf16(kh0, qhf[ds], s0, 0, 0, 0);
        s0 = __builtin_amdgcn_mfma_f32_32x32x16_bf16(kh0, qlf[ds], s0, 0, 0, 0);
        s0 = __builtin_amdgcn_mfma_f32_32x32x16_bf16(kl0, qhf[ds], s0, 0, 0, 0);
        s1 = __builtin_amdgcn_mfma_f32_32x32x16_bf16(kh1, qhf[ds], s1, 0, 0, 0);
        s1 = __builtin_amdgcn_mfma_f32_32x32x16_bf16(kh1, qlf[ds], s1, 0, 0, 0);
        s1 = __builtin_amdgcn_mfma_f32_32x32x16_bf16(kl1, qhf[ds], s1, 0, 0, 0);
      }
    }

    // threefry km0 (fills s1's MFMA chain latency)
    const uint32_t F0 = Fq + (uint32_t)kb;
    const uint32_t pk0 = sample16(s0, F0);

    __syncthreads();  // all K reads done (V[vb] is double-buffered, still live)
    if (kt < 15) stage(kb + 64, (kt & 1) ^ 1);

    // staging latency hidden under: PV km0 + threefry km1 + PV km1
    pv16(pk0, 0, vb);
    const uint32_t pk1 = sample16(s1, F0 + 32u);
    pv16(pk1, 1, vb);
  }

  // epilogue: O^T C-layout col=q(l31), row=d=(reg&3)+8*(reg>>2)+4h+dm*32
  const int b = bh >> 4, hh = bh & 15;
  const size_t rowbase = ((size_t)(b * 2048 + q_lane)) * 1024 + hh * 64;
#pragma unroll
  for (int dm = 0; dm < 2; ++dm) {
#pragma unroll
    for (int a = 0; a < 4; ++a) {
      us4 v;
#pragma unroll
      for (int c = 0; c < 4; ++c)
        v[c] = bf16_rne(dm == 0 ? oacc0[a * 4 + c] : oacc1[a * 4 + c]);
      const int d0 = dm * 32 + 8 * a + 4 * h;
      *(us4*)&AOp[rowbase + d0] = v;
    }
  }
}

// ---------------- kernel 3: output projection, bf16 MFMA ----------------
// A-staging combines the two k-split partials (bf16 unpack-add-repack).
__global__ __launch_bounds__(256) void k_out(
    const unsigned short* __restrict__ A0, const unsigned short* __restrict__ A1,
    const unsigned short* __restrict__ Bw,
    const float* __restrict__ out_b, float* __restrict__ out) {
  __shared__ unsigned short As[128 * 32], Bs[128 * 32];
  const int tid = threadIdx.x;
  const int lane = tid & 63, wid = tid >> 6;
  const int wm = wid >> 1, wn = wid & 1;
  const int bn = blockIdx.x, bm = blockIdx.y;
  const int quad = lane >> 4, c16 = lane & 15;
  const int ldrow = lane >> 2;
  const int ldk = (lane & 3) * 8;

  f4 acc[4][4];
#pragma unroll
  for (int a = 0; a < 4; ++a)
#pragma unroll
    for (int b = 0; b < 4; ++b) { f4 z = {0.f, 0.f, 0.f, 0.f}; acc[a][b] = z; }

  for (int kt = 0; kt < 32; ++kt) {
    const int k0 = kt * 32;
    __syncthreads();
#pragma unroll
    for (int r = 0; r < 2; ++r) {
      const int c = wid + r * 4;
      const int grow = c * 16 + ldrow;
      const size_t ao = (size_t)(bm * 128 + grow) * 1024 + k0 + ldk;
      const size_t bo = (size_t)(bn * 128 + grow) * 1024 + k0 + ldk;
      const int lo = c * 512 + lane * 8;
      const short8 a0 = *(const short8*)&A0[ao];
      const short8 a1 = *(const short8*)&A1[ao];
      short8 acm;
#pragma unroll
      for (int j = 0; j < 8; ++j)
        acm[j] = (short)bf16_rne(bf16_f32((unsigned short)a0[j]) +
                                 bf16_f32((unsigned short)a1[j]));
      *(short8*)&As[lo] = acm;
      gl2lds16(Bw + bo, &Bs[lo]);
    }
    __syncthreads();

    short8 af[4], bf[4];
#pragma unroll
    for (int t = 0; t < 4; ++t) {
      af[t] = *(const short8*)&As[(wm * 64 + t * 16 + c16) * 32 + quad * 8];
      bf[t] = *(const short8*)&Bs[(wn * 64 + t * 16 + c16) * 32 + quad * 8];
    }
#pragma unroll
    for (int tm = 0; tm < 4; ++tm)
#pragma unroll
      for (int tn = 0; tn < 4; ++tn)
        acc[tm][tn] = __builtin_amdgcn_mfma_f32_16x16x32_bf16(af[tm], bf[tn], acc[tm][tn], 0, 0, 0);
  }

#pragma unroll
  for (int tm = 0; tm < 4; ++tm) {
#pragma unroll
    for (int tn = 0; tn < 4; ++tn) {
      const int j = bn * 128 + wn * 64 + tn * 16 + c16;
      const float bias = out_b[j];
#pragma unroll
      for (int r = 0; r < 4; ++r) {
        const int i = bm * 128 + wm * 64 + tm * 16 + quad * 4 + r;
        out[(size_t)i * 1024 + j] = acc[tm][tn][r] + bias;
      }
    }
  }
}

extern "C" void kernel_launch(void* const* d_in, const int* in_sizes, int n_in,
                              void* d_out, int out_size, void* d_ws, size_t ws_size,
                              hipStream_t stream) {
  const float* x     = (const float*)d_in[0];
  const float* qkv_w = (const float*)d_in[3];
  const float* qkv_b = (const float*)d_in[4];
  const float* out_w = (const float*)d_in[5];
  const float* out_b = (const float*)d_in[6];
  float* out = (float*)d_out;

  // workspace carve (ushorts); AO partials alias xh+xl (dead after k_qkv)
  unsigned short* xh  = (unsigned short*)d_ws;        // 4194304
  unsigned short* xl  = xh + 4194304;                 // 4194304
  unsigned short* wh  = xl + 4194304;                 // 3145728
  unsigned short* wl  = wh + 3145728;                 // 3145728
  unsigned short* woh = wl + 3145728;                 // 1048576
  unsigned short* Vt  = woh + 1048576;                // 4194304
  unsigned short* Qh  = Vt + 4194304;                 // 4194304
  unsigned short* Ql  = Qh + 4194304;                 // 4194304
  unsigned short* Kh  = Ql + 4194304;                 // 4194304
  unsigned short* Kl  = Kh + 4194304;                 // 4194304
  unsigned short* AO0 = xh;                           // alias (ks=0 partial)
  unsigned short* AO1 = xl;                           // alias (ks=1 partial)

  k_split<<<8192, 256, 0, stream>>>(x, qkv_w, out_w, xh, xl, wh, wl, woh);
  k_qkv<<<dim3(24, 32), 256, 0, stream>>>(xh, xl, wh, wl, qkv_b, Qh, Ql, Kh, Kl, Vt);
  k_attn<<<dim3(16, 32, 2), 256, 0, stream>>>(Qh, Ql, Kh, Kl, Vt, AO0);
  k_out<<<dim3(8, 32), 256, 0, stream>>>(AO0, AO1, woh, out_b, out);
}

// Round 6
// 533.334 us; speedup vs baseline: 1.0540x; 1.0056x over previous
//
#include <hip/hip_runtime.h>
#include <stdint.h>

// Problem constants
#define NB 2
#define NS 2048
#define NE 1024
#define NH 16
#define ND 64

typedef __attribute__((ext_vector_type(8))) short short8;
typedef __attribute__((ext_vector_type(4))) float f4;
typedef __attribute__((ext_vector_type(16))) float f16v;
typedef __attribute__((ext_vector_type(4))) unsigned short us4;

static __device__ __forceinline__ unsigned short bf16_rne(float x) {
  uint32_t u = __builtin_bit_cast(uint32_t, x);
  u += 0x7fffu + ((u >> 16) & 1u);
  return (unsigned short)(u >> 16);
}
static __device__ __forceinline__ float bf16_f32(unsigned short h) {
  uint32_t u = ((uint32_t)h) << 16;
  return __builtin_bit_cast(float, u);
}

// JAX threefry2x32, key = (0, 42), 20 rounds.
static __device__ __forceinline__ void threefry42(uint32_t x0, uint32_t x1,
                                                  uint32_t& o0, uint32_t& o1) {
  const uint32_t ks0 = 0u, ks1 = 42u;
  const uint32_t ks2 = 0u ^ 42u ^ 0x1BD11BDAu;
  x0 += ks0; x1 += ks1;
#define TF4(a,b,c,d) \
  x0 += x1; x1 = __builtin_rotateleft32(x1, a); x1 ^= x0; \
  x0 += x1; x1 = __builtin_rotateleft32(x1, b); x1 ^= x0; \
  x0 += x1; x1 = __builtin_rotateleft32(x1, c); x1 ^= x0; \
  x0 += x1; x1 = __builtin_rotateleft32(x1, d); x1 ^= x0;
  TF4(13,15,26,6)  x0 += ks1; x1 += ks2 + 1u;
  TF4(17,29,16,24) x0 += ks2; x1 += ks0 + 2u;
  TF4(13,15,26,6)  x0 += ks0; x1 += ks1 + 3u;
  TF4(17,29,16,24) x0 += ks1; x1 += ks2 + 4u;
  TF4(13,15,26,6)  x0 += ks2; x1 += ks0 + 5u;
#undef TF4
  o0 = x0; o1 = x1;
}

// async global->LDS 16B/lane.
static __device__ __forceinline__ void gl2lds16(const void* g, void* l) {
  __builtin_amdgcn_global_load_lds(
      (const __attribute__((address_space(1))) uint32_t*)g,
      (__attribute__((address_space(3))) uint32_t*)l, 16, 0, 0);
}

// ---------------- kernel 0: split fp32 -> bf16 hi/lo ----------------
__global__ void k_split(const float* __restrict__ x, const float* __restrict__ qw,
                        const float* __restrict__ ow,
                        unsigned short* __restrict__ xh, unsigned short* __restrict__ xl,
                        unsigned short* __restrict__ wh, unsigned short* __restrict__ wl,
                        unsigned short* __restrict__ woh) {
  for (uint32_t i = blockIdx.x * 256u + threadIdx.x; i < 8388608u; i += gridDim.x * 256u) {
    if (i < 4194304u) {
      float v = x[i];
      unsigned short hi = bf16_rne(v);
      xh[i] = hi;
      xl[i] = bf16_rne(v - bf16_f32(hi));
    } else if (i < 7340032u) {
      uint32_t j = i - 4194304u;
      float v = qw[j];
      unsigned short hi = bf16_rne(v);
      wh[j] = hi;
      wl[j] = bf16_rne(v - bf16_f32(hi));
    } else {
      uint32_t j = i - 7340032u;
      woh[j] = bf16_rne(ow[j]);
    }
  }
}

// ---------------- kernel 1: QKV GEMM, split-bf16 MFMA ----------------
__global__ __launch_bounds__(256) void k_qkv(
    const unsigned short* __restrict__ xh, const unsigned short* __restrict__ xl,
    const unsigned short* __restrict__ wh, const unsigned short* __restrict__ wl,
    const float* __restrict__ qkv_b,
    unsigned short* __restrict__ Qh, unsigned short* __restrict__ Ql,
    unsigned short* __restrict__ Kh, unsigned short* __restrict__ Kl,
    unsigned short* __restrict__ Vt) {
  __shared__ unsigned short SM[16384];  // 32KB, carved; reused by V transpose
  unsigned short* Ah = SM;
  unsigned short* Al = SM + 4096;
  unsigned short* Bh = SM + 8192;
  unsigned short* Bl = SM + 12288;
  const int tid = threadIdx.x;
  const int lane = tid & 63, wid = tid >> 6;
  const int wm = wid >> 1, wn = wid & 1;
  const int bn = blockIdx.x, bm = blockIdx.y;
  const bool isV = (bn >= 16);
  const int quad = lane >> 4, c16 = lane & 15;
  const int ldrow = lane >> 2;
  const int ldk = (lane & 3) * 8;

  f4 acc[4][4];
#pragma unroll
  for (int a = 0; a < 4; ++a)
#pragma unroll
    for (int b = 0; b < 4; ++b) { f4 z = {0.f, 0.f, 0.f, 0.f}; acc[a][b] = z; }

  for (int kt = 0; kt < 32; ++kt) {
    const int k0 = kt * 32;
    __syncthreads();
#pragma unroll
    for (int r = 0; r < 2; ++r) {
      const int c = wid + r * 4;
      const int grow = c * 16 + ldrow;
      const size_t ao = (size_t)(bm * 128 + grow) * 1024 + k0 + ldk;
      const size_t bo = (size_t)(bn * 128 + grow) * 1024 + k0 + ldk;
      const int lo = c * 512 + lane * 8;
      gl2lds16(xh + ao, &Ah[lo]);
      gl2lds16(wh + bo, &Bh[lo]);
      if (!isV) {
        gl2lds16(xl + ao, &Al[lo]);
        gl2lds16(wl + bo, &Bl[lo]);
      }
    }
    __syncthreads();

    short8 ah[4], al[4], bhf[4], blf[4];
#pragma unroll
    for (int t = 0; t < 4; ++t) {
      ah[t] = *(const short8*)&Ah[(wm * 64 + t * 16 + c16) * 32 + quad * 8];
      bhf[t] = *(const short8*)&Bh[(wn * 64 + t * 16 + c16) * 32 + quad * 8];
      if (!isV) {
        al[t] = *(const short8*)&Al[(wm * 64 + t * 16 + c16) * 32 + quad * 8];
        blf[t] = *(const short8*)&Bl[(wn * 64 + t * 16 + c16) * 32 + quad * 8];
      }
    }
    if (isV) {
#pragma unroll
      for (int tm = 0; tm < 4; ++tm)
#pragma unroll
        for (int tn = 0; tn < 4; ++tn)
          acc[tm][tn] = __builtin_amdgcn_mfma_f32_16x16x32_bf16(ah[tm], bhf[tn], acc[tm][tn], 0, 0, 0);
    } else {
#pragma unroll
      for (int tm = 0; tm < 4; ++tm)
#pragma unroll
        for (int tn = 0; tn < 4; ++tn) {
          acc[tm][tn] = __builtin_amdgcn_mfma_f32_16x16x32_bf16(ah[tm], bhf[tn], acc[tm][tn], 0, 0, 0);
          acc[tm][tn] = __builtin_amdgcn_mfma_f32_16x16x32_bf16(ah[tm], blf[tn], acc[tm][tn], 0, 0, 0);
          acc[tm][tn] = __builtin_amdgcn_mfma_f32_16x16x32_bf16(al[tm], bhf[tn], acc[tm][tn], 0, 0, 0);
        }
    }
  }

  if (!isV) {
#pragma unroll
    for (int tm = 0; tm < 4; ++tm) {
#pragma unroll
      for (int tn = 0; tn < 4; ++tn) {
        const int j = bn * 128 + wn * 64 + tn * 16 + c16;
        const float bias = qkv_b[j];
        const int which = j >> 10;
        const int rem = j & 1023;
        const int h = rem >> 6, d = rem & 63;
#pragma unroll
        for (int r = 0; r < 4; ++r) {
          const int i = bm * 128 + wm * 64 + tm * 16 + quad * 4 + r;
          const int b = i >> 11, s = i & 2047;
          const size_t off = (((size_t)(b * 16 + h)) * 2048 + (size_t)s) * 64 + d;
          const float v = acc[tm][tn][r] + bias;
          const unsigned short hi = bf16_rne(v);
          const unsigned short lo = bf16_rne(v - bf16_f32(hi));
          if (which == 0) { Qh[off] = hi; Ql[off] = lo; }
          else            { Kh[off] = hi; Kl[off] = lo; }
        }
      }
    }
  } else {
    __syncthreads();
#pragma unroll
    for (int tm = 0; tm < 4; ++tm) {
#pragma unroll
      for (int tn = 0; tn < 4; ++tn) {
        const int j = bn * 128 + wn * 64 + tn * 16 + c16;
        const float bias = qkv_b[j];
        const int d_local = wn * 64 + tn * 16 + c16;
#pragma unroll
        for (int r = 0; r < 4; ++r) {
          const int s_local = wm * 64 + tm * 16 + quad * 4 + r;
          SM[d_local * 128 + s_local] = bf16_rne(acc[tm][tn][r] + bias);
        }
      }
    }
    __syncthreads();
    const int b = (bm * 128) >> 11;
    const int s0 = (bm * 128) & 2047;
    const int h2 = (bn - 16) * 2;
#pragma unroll
    for (int it = 0; it < 8; ++it) {
      const int chunk = it * 256 + tid;
      const int dr = chunk >> 4;
      const int sc = (chunk & 15) * 8;
      const short8 v = *(const short8*)&SM[dr * 128 + sc];
      const int bh = b * 16 + h2 + (dr >> 6);
      const int d = dr & 63;
      *(short8*)&Vt[((size_t)bh * 64 + d) * 2048 + s0 + sc] = v;
    }
  }
}

// ---------------- kernel 2: MFMA flash attention + exact threefry sampling ----
// Round-6: CONSOLIDATION. R0-R5 established k_attn is pinned at ~330us across
// 3x LDS-traffic change, 2x occupancy change, and MFMA-shape change -> the
// duration tracks only the threefry int-ALU stream (~283us floor if wave64
// int VALU issues at 4cyc; measured 330 incl. MFMA/barrier residual). k_attn
// is at its integer-ALU roofline; structural changes are done. This round
// removes the k-split (occupancy proven irrelevant) so k_out loses its
// VALU-heavy partial-combine: z=1, 512 blocks, single AO, full 32-kt loop.
// Structure otherwise identical to the verified R5 kernel (32x32 swapped
// S^T = K.Q^T, lane-local P, Vt as PV A-operand).
__global__ __launch_bounds__(256) void k_attn(
    const unsigned short* __restrict__ Qh, const unsigned short* __restrict__ Ql,
    const unsigned short* __restrict__ Khg, const unsigned short* __restrict__ Klg,
    const unsigned short* __restrict__ Vtg, unsigned short* __restrict__ AO) {
  __shared__ unsigned short Ksh[4096], Ksl[4096], Vs[8192];
  const int tid = threadIdx.x;
  const int lane = tid & 63, w = tid >> 6;
  const int l31 = lane & 31, h = lane >> 5;
  const int q0 = blockIdx.x * 128;
  const int bh = blockIdx.y;
  const size_t base = (size_t)bh * (size_t)(2048 * 64);
  const int q_lane = q0 + w * 32 + l31;             // this lane's q row

  // Q B-fragments (col=q=l31, k-dim=d): element j of frag ds -> d = ds*16+h*8+j
  const size_t qoff = base + (size_t)q_lane * 64 + h * 8;
  short8 qhf[4], qlf[4];
#pragma unroll
  for (int ds = 0; ds < 4; ++ds) {
    qhf[ds] = *(const short8*)&Qh[qoff + ds * 16];
    qlf[ds] = *(const short8*)&Ql[qoff + ds * 16];
  }

  // threefry flat base: f = bh*2^22 + q*2048 + k; this lane's k-rows are
  // km*32 + (rg&3) + 8*(rg>>2) + 4*h  (S^T C-layout row mapping)
  const uint32_t Fq = (uint32_t)bh * 4194304u + (uint32_t)q_lane * 2048u + 4u * (uint32_t)h;

  // swizzled staging indices (R0-proven): LDS chunk c holds global chunk of
  // row r=c>>3 rotated by r; reads use ((chunk + row)&7).
  const int c0 = tid, r0 = c0 >> 3, g0 = ((c0 & 7) - r0) & 7;
  const int c1 = tid + 256, r1 = c1 >> 3, g1 = ((c1 & 7) - r1) & 7;
  const int swidx = (lane ^ 32) << 2;               // bpermute half-swap index

  auto stage = [&](int kb, int vbuf) {
    const size_t koff = base + (size_t)kb * 64;
    gl2lds16(Khg + koff + r0 * 64 + g0 * 8, &Ksh[c0 * 8]);
    gl2lds16(Klg + koff + r0 * 64 + g0 * 8, &Ksl[c0 * 8]);
    gl2lds16(Vtg + base + (size_t)r0 * 2048 + kb + g0 * 8, &Vs[vbuf * 4096 + c0 * 8]);
    gl2lds16(Khg + koff + r1 * 64 + g1 * 8, &Ksh[c1 * 8]);
    gl2lds16(Klg + koff + r1 * 64 + g1 * 8, &Ksl[c1 * 8]);
    gl2lds16(Vtg + base + (size_t)r1 * 2048 + kb + g1 * 8, &Vs[vbuf * 4096 + c1 * 8]);
  };

  f16v oacc0 = {0.f,0.f,0.f,0.f,0.f,0.f,0.f,0.f,0.f,0.f,0.f,0.f,0.f,0.f,0.f,0.f};
  f16v oacc1 = oacc0;

  stage(0, 0);

  // threefry+sample for one 16-reg S^T accumulator -> 16-bit mask
  auto sample16 = [&](const f16v& s, uint32_t F) -> uint32_t {
    uint32_t pk = 0u;
#pragma unroll
    for (int rg = 0; rg < 16; ++rg) {
      uint32_t o0, o1;
      threefry42(0u, F + (uint32_t)((rg & 3) + 8 * (rg >> 2)), o0, o1);
      const float m = (float)((o0 ^ o1) >> 9);
      const float e = __builtin_amdgcn_exp2f(s[rg] * -0.18033688f);
      if (fmaf(m, e, m) < 8388608.0f) pk |= (1u << rg);
    }
    return pk;
  };

  // PV for one k-mtile: bits -> B-frags -> 4 MFMAs (2 ksteps x 2 d-mtiles)
  auto pv16 = [&](uint32_t pk, int km, int vb) {
    const uint32_t pksw = (uint32_t)__builtin_amdgcn_ds_bpermute(swidx, (int)pk);
    const uint32_t ph0 = h ? pksw : pk;   // bits held by lane-half 0 (rows r%8<4)
    const uint32_t ph1 = h ? pk : pksw;   // bits held by lane-half 1
#pragma unroll
    for (int k2 = 0; k2 < 2; ++k2) {
      const int bb = (k2 * 2 + h) * 4;    // nibble base: blk = 2*ks' + h_cons
      const uint32_t nl = (ph0 >> bb) & 15u;
      const uint32_t nh = (ph1 >> bb) & 15u;
      short8 pf;
#pragma unroll
      for (int j = 0; j < 4; ++j) {
        pf[j]     = (nl & (1u << j)) ? (short)0x3F80 : (short)0;
        pf[j + 4] = (nh & (1u << j)) ? (short)0x3F80 : (short)0;
      }
      const int vch = (km * 2 + k2) * 2 + h;  // V k-chunk for this frag
#pragma unroll
      for (int dm = 0; dm < 2; ++dm) {
        const int vrow = dm * 32 + l31;
        const short8 vf = *(const short8*)&Vs[vb + vrow * 64 + ((vch + vrow) & 7) * 8];
        if (dm == 0) oacc0 = __builtin_amdgcn_mfma_f32_32x32x16_bf16(vf, pf, oacc0, 0, 0, 0);
        else         oacc1 = __builtin_amdgcn_mfma_f32_32x32x16_bf16(vf, pf, oacc1, 0, 0, 0);
      }
    }
  };

  for (int kt = 0; kt < 32; ++kt) {
    const int kb = kt * 64;
    const int vb = (kt & 1) * 4096;
    __syncthreads();  // tile kb staged; all waves past previous compute

    // S^T = K.Q^T, split-bf16 3 passes, both k-mtiles (24 MFMAs, 16KB K reads)
    f16v s0 = {0.f,0.f,0.f,0.f,0.f,0.f,0.f,0.f,0.f,0.f,0.f,0.f,0.f,0.f,0.f,0.f};
    f16v s1 = s0;
    {
      const int krow0 = l31, krow1 = 32 + l31;
#pragma unroll
      for (int ds = 0; ds < 4; ++ds) {
        const int ch = ds * 2 + h;
        const int off0 = krow0 * 64 + ((ch + krow0) & 7) * 8;
        const int off1 = krow1 * 64 + ((ch + krow1) & 7) * 8;
        const short8 kh0 = *(const short8*)&Ksh[off0];
        const short8 kl0 = *(const short8*)&Ksl[off0];
        const short8 kh1 = *(const short8*)&Ksh[off1];
        const short8 kl1 = *(const short8*)&Ksl[off1];
        s0 = __builtin_amdgcn_mfma_f32_32x32x16_bf16(kh0, qhf[ds], s0, 0, 0, 0);
        s0 = __builtin_amdgcn_mfma_f32_32x32x16_bf16(kh0, qlf[ds], s0, 0, 0, 0);
        s0 = __builtin_amdgcn_mfma_f32_32x32x16_bf16(kl0, qhf[ds], s0, 0, 0, 0);
        s1 = __builtin_amdgcn_mfma_f32_32x32x16_bf16(kh1, qhf[ds], s1, 0, 0, 0);
        s1 = __builtin_amdgcn_mfma_f32_32x32x16_bf16(kh1, qlf[ds], s1, 0, 0, 0);
        s1 = __builtin_amdgcn_mfma_f32_32x32x16_bf16(kl1, qhf[ds], s1, 0, 0, 0);
      }
    }

    // threefry km0 (fills s1's MFMA chain latency)
    const uint32_t F0 = Fq + (uint32_t)kb;
    const uint32_t pk0 = sample16(s0, F0);

    __syncthreads();  // all K reads done (V[vb] is double-buffered, still live)
    if (kt < 31) stage(kb + 64, (kt & 1) ^ 1);

    // staging latency hidden under: PV km0 + threefry km1 + PV km1
    pv16(pk0, 0, vb);
    const uint32_t pk1 = sample16(s1, F0 + 32u);
    pv16(pk1, 1, vb);
  }

  // epilogue: O^T C-layout col=q(l31), row=d=(reg&3)+8*(reg>>2)+4h+dm*32
  const int b = bh >> 4, hh = bh & 15;
  const size_t rowbase = ((size_t)(b * 2048 + q_lane)) * 1024 + hh * 64;
#pragma unroll
  for (int dm = 0; dm < 2; ++dm) {
#pragma unroll
    for (int a = 0; a < 4; ++a) {
      us4 v;
#pragma unroll
      for (int c = 0; c < 4; ++c)
        v[c] = bf16_rne(dm == 0 ? oacc0[a * 4 + c] : oacc1[a * 4 + c]);
      const int d0 = dm * 32 + 8 * a + 4 * h;
      *(us4*)&AO[rowbase + d0] = v;
    }
  }
}

// ---------------- kernel 3: output projection, bf16 MFMA (R0 form) ----------
__global__ __launch_bounds__(256) void k_out(
    const unsigned short* __restrict__ A, const unsigned short* __restrict__ Bw,
    const float* __restrict__ out_b, float* __restrict__ out) {
  __shared__ unsigned short As[128 * 32], Bs[128 * 32];
  const int tid = threadIdx.x;
  const int lane = tid & 63, wid = tid >> 6;
  const int wm = wid >> 1, wn = wid & 1;
  const int bn = blockIdx.x, bm = blockIdx.y;
  const int quad = lane >> 4, c16 = lane & 15;
  const int ldrow = lane >> 2;
  const int ldk = (lane & 3) * 8;

  f4 acc[4][4];
#pragma unroll
  for (int a = 0; a < 4; ++a)
#pragma unroll
    for (int b = 0; b < 4; ++b) { f4 z = {0.f, 0.f, 0.f, 0.f}; acc[a][b] = z; }

  for (int kt = 0; kt < 32; ++kt) {
    const int k0 = kt * 32;
    __syncthreads();
#pragma unroll
    for (int r = 0; r < 2; ++r) {
      const int c = wid + r * 4;
      const int grow = c * 16 + ldrow;
      const size_t ao = (size_t)(bm * 128 + grow) * 1024 + k0 + ldk;
      const size_t bo = (size_t)(bn * 128 + grow) * 1024 + k0 + ldk;
      const int lo = c * 512 + lane * 8;
      gl2lds16(A + ao, &As[lo]);
      gl2lds16(Bw + bo, &Bs[lo]);
    }
    __syncthreads();

    short8 af[4], bf[4];
#pragma unroll
    for (int t = 0; t < 4; ++t) {
      af[t] = *(const short8*)&As[(wm * 64 + t * 16 + c16) * 32 + quad * 8];
      bf[t] = *(const short8*)&Bs[(wn * 64 + t * 16 + c16) * 32 + quad * 8];
    }
#pragma unroll
    for (int tm = 0; tm < 4; ++tm)
#pragma unroll
      for (int tn = 0; tn < 4; ++tn)
        acc[tm][tn] = __builtin_amdgcn_mfma_f32_16x16x32_bf16(af[tm], bf[tn], acc[tm][tn], 0, 0, 0);
  }

#pragma unroll
  for (int tm = 0; tm < 4; ++tm) {
#pragma unroll
    for (int tn = 0; tn < 4; ++tn) {
      const int j = bn * 128 + wn * 64 + tn * 16 + c16;
      const float bias = out_b[j];
#pragma unroll
      for (int r = 0; r < 4; ++r) {
        const int i = bm * 128 + wm * 64 + tm * 16 + quad * 4 + r;
        out[(size_t)i * 1024 + j] = acc[tm][tn][r] + bias;
      }
    }
  }
}

extern "C" void kernel_launch(void* const* d_in, const int* in_sizes, int n_in,
                              void* d_out, int out_size, void* d_ws, size_t ws_size,
                              hipStream_t stream) {
  const float* x     = (const float*)d_in[0];
  const float* qkv_w = (const float*)d_in[3];
  const float* qkv_b = (const float*)d_in[4];
  const float* out_w = (const float*)d_in[5];
  const float* out_b = (const float*)d_in[6];
  float* out = (float*)d_out;

  // workspace carve (ushorts); AO aliases xh (xh dead after k_qkv)
  unsigned short* xh  = (unsigned short*)d_ws;        // 4194304
  unsigned short* xl  = xh + 4194304;                 // 4194304
  unsigned short* wh  = xl + 4194304;                 // 3145728
  unsigned short* wl  = wh + 3145728;                 // 3145728
  unsigned short* woh = wl + 3145728;                 // 1048576
  unsigned short* Vt  = woh + 1048576;                // 4194304
  unsigned short* Qh  = Vt + 4194304;                 // 4194304
  unsigned short* Ql  = Qh + 4194304;                 // 4194304
  unsigned short* Kh  = Ql + 4194304;                 // 4194304
  unsigned short* Kl  = Kh + 4194304;                 // 4194304
  unsigned short* AO  = xh;                           // alias

  k_split<<<8192, 256, 0, stream>>>(x, qkv_w, out_w, xh, xl, wh, wl, woh);
  k_qkv<<<dim3(24, 32), 256, 0, stream>>>(xh, xl, wh, wl, qkv_b, Qh, Ql, Kh, Kl, Vt);
  k_attn<<<dim3(16, 32), 256, 0, stream>>>(Qh, Ql, Kh, Kl, Vt, AO);
  k_out<<<dim3(8, 32), 256, 0, stream>>>(AO, woh, out_b, out);
}

// Round 7
// 502.739 us; speedup vs baseline: 1.1182x; 1.0609x over previous
//
#include <hip/hip_runtime.h>
#include <stdint.h>

// Problem constants
#define NB 2
#define NS 2048
#define NE 1024
#define NH 16
#define ND 64

typedef __attribute__((ext_vector_type(8))) short short8;
typedef __attribute__((ext_vector_type(4))) float f4;
typedef __attribute__((ext_vector_type(16))) float f16v;
typedef __attribute__((ext_vector_type(4))) unsigned short us4;

static __device__ __forceinline__ unsigned short bf16_rne(float x) {
  uint32_t u = __builtin_bit_cast(uint32_t, x);
  u += 0x7fffu + ((u >> 16) & 1u);
  return (unsigned short)(u >> 16);
}
static __device__ __forceinline__ float bf16_f32(unsigned short h) {
  uint32_t u = ((uint32_t)h) << 16;
  return __builtin_bit_cast(float, u);
}

// JAX threefry2x32, key = (0, 42), 20 rounds.
static __device__ __forceinline__ void threefry42(uint32_t x0, uint32_t x1,
                                                  uint32_t& o0, uint32_t& o1) {
  const uint32_t ks0 = 0u, ks1 = 42u;
  const uint32_t ks2 = 0u ^ 42u ^ 0x1BD11BDAu;
  x0 += ks0; x1 += ks1;
#define TF4(a,b,c,d) \
  x0 += x1; x1 = __builtin_rotateleft32(x1, a); x1 ^= x0; \
  x0 += x1; x1 = __builtin_rotateleft32(x1, b); x1 ^= x0; \
  x0 += x1; x1 = __builtin_rotateleft32(x1, c); x1 ^= x0; \
  x0 += x1; x1 = __builtin_rotateleft32(x1, d); x1 ^= x0;
  TF4(13,15,26,6)  x0 += ks1; x1 += ks2 + 1u;
  TF4(17,29,16,24) x0 += ks2; x1 += ks0 + 2u;
  TF4(13,15,26,6)  x0 += ks0; x1 += ks1 + 3u;
  TF4(17,29,16,24) x0 += ks1; x1 += ks2 + 4u;
  TF4(13,15,26,6)  x0 += ks2; x1 += ks0 + 5u;
#undef TF4
  o0 = x0; o1 = x1;
}

// async global->LDS 16B/lane.
static __device__ __forceinline__ void gl2lds16(const void* g, void* l) {
  __builtin_amdgcn_global_load_lds(
      (const __attribute__((address_space(1))) uint32_t*)g,
      (__attribute__((address_space(3))) uint32_t*)l, 16, 0, 0);
}

// ---------------- kernel 0: split fp32 -> bf16 hi/lo ----------------
__global__ void k_split(const float* __restrict__ x, const float* __restrict__ qw,
                        const float* __restrict__ ow,
                        unsigned short* __restrict__ xh, unsigned short* __restrict__ xl,
                        unsigned short* __restrict__ wh, unsigned short* __restrict__ wl,
                        unsigned short* __restrict__ woh) {
  for (uint32_t i = blockIdx.x * 256u + threadIdx.x; i < 8388608u; i += gridDim.x * 256u) {
    if (i < 4194304u) {
      float v = x[i];
      unsigned short hi = bf16_rne(v);
      xh[i] = hi;
      xl[i] = bf16_rne(v - bf16_f32(hi));
    } else if (i < 7340032u) {
      uint32_t j = i - 4194304u;
      float v = qw[j];
      unsigned short hi = bf16_rne(v);
      wh[j] = hi;
      wl[j] = bf16_rne(v - bf16_f32(hi));
    } else {
      uint32_t j = i - 7340032u;
      woh[j] = bf16_rne(ow[j]);
    }
  }
}

// ---------------- kernel 1: QKV GEMM, 32x32 split-bf16 MFMA -----------------
// Round-7: k_qkv pipe diet. (a) 16x16x32 -> 32x32x16 MFMAs: same FLOP in half
// the instructions on the faster pipe (2382 vs 2075 TF ubench). (b) LDS frag
// reads swizzled: rows are 64B (4 chunks of 16B); physical chunk
// pc = (lc + (row>>1)) & 3 spreads lanes over all 8 (parity x chunk) bank
// slots (4-way max vs 8-16-way unswizzled). Staging keeps LDS LINEAR
// (gl2lds requirement) and pre-swizzles the GLOBAL source column instead:
// gchunk = ((lane&3) - ((lane>>3)&3)) & 3.
// Q,K blocks (bn<16): 3-pass split-bf16. V blocks (bn>=16): 1-pass + LDS
// transpose epilogue -> coalesced Vt stores.
__global__ __launch_bounds__(256) void k_qkv(
    const unsigned short* __restrict__ xh, const unsigned short* __restrict__ xl,
    const unsigned short* __restrict__ wh, const unsigned short* __restrict__ wl,
    const float* __restrict__ qkv_b,
    unsigned short* __restrict__ Qh, unsigned short* __restrict__ Ql,
    unsigned short* __restrict__ Kh, unsigned short* __restrict__ Kl,
    unsigned short* __restrict__ Vt) {
  __shared__ unsigned short SM[16384];  // 32KB, carved; reused by V transpose
  unsigned short* Ah = SM;
  unsigned short* Al = SM + 4096;
  unsigned short* Bh = SM + 8192;
  unsigned short* Bl = SM + 12288;
  const int tid = threadIdx.x;
  const int lane = tid & 63, wid = tid >> 6;
  const int wm = wid >> 1, wn = wid & 1;
  const int bn = blockIdx.x, bm = blockIdx.y;
  const bool isV = (bn >= 16);
  const int l31 = lane & 31, h = lane >> 5;
  const int ldrow = lane >> 2;
  // swizzled global source chunk (see header comment)
  const int ldk = (((lane & 3) - ((lane >> 3) & 3)) & 3) * 8;
  // read-side physical-chunk rotation base: (row>>1)&3 == (l31>>1)&3
  const int rot = (l31 >> 1) & 3;

  f16v acc[2][2];
#pragma unroll
  for (int a = 0; a < 2; ++a)
#pragma unroll
    for (int b = 0; b < 2; ++b)
      acc[a][b] = (f16v){0.f,0.f,0.f,0.f,0.f,0.f,0.f,0.f,0.f,0.f,0.f,0.f,0.f,0.f,0.f,0.f};

  for (int kt = 0; kt < 32; ++kt) {
    const int k0 = kt * 32;
    __syncthreads();
#pragma unroll
    for (int r = 0; r < 2; ++r) {
      const int c = wid + r * 4;
      const int grow = c * 16 + ldrow;
      const size_t ao = (size_t)(bm * 128 + grow) * 1024 + k0 + ldk;
      const size_t bo = (size_t)(bn * 128 + grow) * 1024 + k0 + ldk;
      const int lo = c * 512 + lane * 8;
      gl2lds16(xh + ao, &Ah[lo]);
      gl2lds16(wh + bo, &Bh[lo]);
      if (!isV) {
        gl2lds16(xl + ao, &Al[lo]);
        gl2lds16(wl + bo, &Bl[lo]);
      }
    }
    __syncthreads();

#pragma unroll
    for (int ks = 0; ks < 2; ++ks) {
      const int lc = ks * 2 + h;          // logical 16B chunk within the row
      const int pcs = ((lc + rot) & 3) * 8;
      short8 af[2], bf_[2], alf[2], blf[2];
#pragma unroll
      for (int t = 0; t < 2; ++t) {
        const int arow = wm * 64 + t * 32 + l31;
        const int brow = wn * 64 + t * 32 + l31;
        af[t]  = *(const short8*)&Ah[arow * 32 + pcs];
        bf_[t] = *(const short8*)&Bh[brow * 32 + pcs];
        if (!isV) {
          alf[t] = *(const short8*)&Al[arow * 32 + pcs];
          blf[t] = *(const short8*)&Bl[brow * 32 + pcs];
        }
      }
      if (isV) {
#pragma unroll
        for (int tm = 0; tm < 2; ++tm)
#pragma unroll
          for (int tn = 0; tn < 2; ++tn)
            acc[tm][tn] = __builtin_amdgcn_mfma_f32_32x32x16_bf16(af[tm], bf_[tn], acc[tm][tn], 0, 0, 0);
      } else {
#pragma unroll
        for (int tm = 0; tm < 2; ++tm)
#pragma unroll
          for (int tn = 0; tn < 2; ++tn) {
            acc[tm][tn] = __builtin_amdgcn_mfma_f32_32x32x16_bf16(af[tm], bf_[tn], acc[tm][tn], 0, 0, 0);
            acc[tm][tn] = __builtin_amdgcn_mfma_f32_32x32x16_bf16(af[tm], blf[tn], acc[tm][tn], 0, 0, 0);
            acc[tm][tn] = __builtin_amdgcn_mfma_f32_32x32x16_bf16(alf[tm], bf_[tn], acc[tm][tn], 0, 0, 0);
          }
      }
    }
  }

  if (!isV) {
    // epilogue Q/K: hi/lo bf16 [bh][s][d]; C-layout col=l31, row=(a&3)+8*(a>>2)+4h
#pragma unroll
    for (int tm = 0; tm < 2; ++tm) {
#pragma unroll
      for (int tn = 0; tn < 2; ++tn) {
        const int j = bn * 128 + wn * 64 + tn * 32 + l31;
        const float bias = qkv_b[j];
        const int which = j >> 10;
        const int rem = j & 1023;
        const int hd = rem >> 6, d = rem & 63;
#pragma unroll
        for (int a = 0; a < 16; ++a) {
          const int m_local = wm * 64 + tm * 32 + (a & 3) + 8 * (a >> 2) + 4 * h;
          const int i = bm * 128 + m_local;
          const int b = i >> 11, s = i & 2047;
          const size_t off = (((size_t)(b * 16 + hd)) * 2048 + (size_t)s) * 64 + d;
          const float v = acc[tm][tn][a] + bias;
          const unsigned short hi = bf16_rne(v);
          const unsigned short lo = bf16_rne(v - bf16_f32(hi));
          if (which == 0) { Qh[off] = hi; Ql[off] = lo; }
          else            { Kh[off] = hi; Kl[off] = lo; }
        }
      }
    }
  } else {
    // epilogue V: LDS transpose [d_local 128][s_local 128], then coalesced Vt
    __syncthreads();
#pragma unroll
    for (int tm = 0; tm < 2; ++tm) {
#pragma unroll
      for (int tn = 0; tn < 2; ++tn) {
        const int d_local = wn * 64 + tn * 32 + l31;
        const float bias = qkv_b[bn * 128 + d_local];
#pragma unroll
        for (int a = 0; a < 16; ++a) {
          const int s_local = wm * 64 + tm * 32 + (a & 3) + 8 * (a >> 2) + 4 * h;
          SM[d_local * 128 + s_local] = bf16_rne(acc[tm][tn][a] + bias);
        }
      }
    }
    __syncthreads();
    const int b = (bm * 128) >> 11;
    const int s0 = (bm * 128) & 2047;
    const int h2 = (bn - 16) * 2;
#pragma unroll
    for (int it = 0; it < 8; ++it) {
      const int chunk = it * 256 + tid;
      const int dr = chunk >> 4;
      const int sc = (chunk & 15) * 8;
      const short8 v = *(const short8*)&SM[dr * 128 + sc];
      const int bh = b * 16 + h2 + (dr >> 6);
      const int d = dr & 63;
      *(short8*)&Vt[((size_t)bh * 64 + d) * 2048 + s0 + sc] = v;
    }
  }
}

// ---------------- kernel 2: MFMA flash attention + exact threefry sampling ----
// EXACT round-0 kernel (proven best: 324.4us, no spills, 0 conflicts).
// R1-R6 bracketed it from every direction (occupancy up/down, LDS traffic /3,
// MFMA shape, phase order) - all neutral or worse. k_attn is pinned at its
// threefry integer-ALU issue floor (~283us + MFMA/barrier residual); closed.
__global__ __launch_bounds__(256) void k_attn(
    const unsigned short* __restrict__ Qh, const unsigned short* __restrict__ Ql,
    const unsigned short* __restrict__ Khg, const unsigned short* __restrict__ Klg,
    const unsigned short* __restrict__ Vtg, unsigned short* __restrict__ AO) {
  __shared__ unsigned short Ksh[4096], Ksl[4096], Vs[8192], Pm[4096];
  const int tid = threadIdx.x;
  const int lane = tid & 63, w = tid >> 6;
  const int quad = lane >> 4, c16 = lane & 15;
  const int q0 = blockIdx.x * 64;
  const int bh = blockIdx.y;
  const size_t base = (size_t)bh * (size_t)(2048 * 64);

  // Q fragments for this wave's 16 rows (A-operand: m=c16, k=quad*8+j)
  const size_t qoff = base + (size_t)(q0 + w * 16 + c16) * 64 + quad * 8;
  const short8 qh0 = *(const short8*)&Qh[qoff];
  const short8 qh1 = *(const short8*)&Qh[qoff + 32];
  const short8 ql0 = *(const short8*)&Ql[qoff];
  const short8 ql1 = *(const short8*)&Ql[qoff + 32];

  // flat-index base for threefry: f = bh*2^22 + q*2048 + k
  const uint32_t fb = (uint32_t)bh * 4194304u +
                      (uint32_t)(q0 + w * 16 + quad * 4) * 2048u + (uint32_t)c16;

  // swizzled staging indices: LDS chunk c holds global chunk ((c&7) - (c>>3)) & 7
  const int c0 = tid, r0 = c0 >> 3, g0 = ((c0 & 7) - r0) & 7;
  const int c1 = tid + 256, r1 = c1 >> 3, g1 = ((c1 & 7) - r1) & 7;

  f4 oacc[4];
#pragma unroll
  for (int s = 0; s < 4; ++s) { f4 z = {0.f, 0.f, 0.f, 0.f}; oacc[s] = z; }

  auto stage = [&](int kb, int vbuf) {
    const size_t koff = base + (size_t)kb * 64;
    gl2lds16(Khg + koff + r0 * 64 + g0 * 8, &Ksh[c0 * 8]);
    gl2lds16(Klg + koff + r0 * 64 + g0 * 8, &Ksl[c0 * 8]);
    gl2lds16(Vtg + base + (size_t)r0 * 2048 + kb + g0 * 8, &Vs[vbuf * 4096 + c0 * 8]);
    gl2lds16(Khg + koff + r1 * 64 + g1 * 8, &Ksh[c1 * 8]);
    gl2lds16(Klg + koff + r1 * 64 + g1 * 8, &Ksl[c1 * 8]);
    gl2lds16(Vtg + base + (size_t)r1 * 2048 + kb + g1 * 8, &Vs[vbuf * 4096 + c1 * 8]);
  };

  stage(0, 0);

  for (int kt = 0; kt < 32; ++kt) {
    const int kb = kt * 64;
    const int vb = (kt & 1) * 4096;
    __syncthreads();  // tile kb staged; all waves past previous compute

    // S = Q.K^T split-bf16 3 passes; K fragments read inline (swizzled rows)
    f4 sacc[4];
#pragma unroll
    for (int sub = 0; sub < 4; ++sub) {
      const int rK = sub * 16 + c16;
      const int sA = ((quad + rK) & 7) * 8;
      const int sB = ((quad + 4 + rK) & 7) * 8;
      const short8 kh0 = *(const short8*)&Ksh[rK * 64 + sA];
      const short8 kh1 = *(const short8*)&Ksh[rK * 64 + sB];
      const short8 kl0 = *(const short8*)&Ksl[rK * 64 + sA];
      const short8 kl1 = *(const short8*)&Ksl[rK * 64 + sB];
      f4 s = {0.f, 0.f, 0.f, 0.f};
      s = __builtin_amdgcn_mfma_f32_16x16x32_bf16(qh0, kh0, s, 0, 0, 0);
      s = __builtin_amdgcn_mfma_f32_16x16x32_bf16(qh1, kh1, s, 0, 0, 0);
      s = __builtin_amdgcn_mfma_f32_16x16x32_bf16(qh0, kl0, s, 0, 0, 0);
      s = __builtin_amdgcn_mfma_f32_16x16x32_bf16(qh1, kl1, s, 0, 0, 0);
      s = __builtin_amdgcn_mfma_f32_16x16x32_bf16(ql0, kh0, s, 0, 0, 0);
      s = __builtin_amdgcn_mfma_f32_16x16x32_bf16(ql1, kh1, s, 0, 0, 0);
      sacc[sub] = s;
    }
    __syncthreads();  // K tile fully consumed by all waves (V[vb] untouched)
    if (kt < 31) stage(kb + 64, (kt & 1) ^ 1);  // lands during threefry below

    // threefry + sigmoid sample -> swizzled Pm (0x3F80 / 0 bf16 mask)
    // u < p  <=>  m*(1+e) < 2^23, m = (float)((o0^o1)>>9), e = 2^(s*-log2e/8)
#pragma unroll
    for (int sub = 0; sub < 4; ++sub) {
      const int qP = sub * 2 + (c16 >> 3);
#pragma unroll
      for (int rr = 0; rr < 4; ++rr) {
        const uint32_t f = fb + (uint32_t)(rr * 2048) + (uint32_t)(kb + sub * 16);
        uint32_t o0, o1;
        threefry42(0u, f, o0, o1);
        const float m = (float)((o0 ^ o1) >> 9);
        const float e = __builtin_amdgcn_exp2f(sacc[sub][rr] * -0.18033688f);
        const int rP = w * 16 + quad * 4 + rr;
        const int addr = rP * 64 + (((qP + rP) & 7) * 8) + (c16 & 7);
        Pm[addr] = (fmaf(m, e, m) < 8388608.0f) ? 0x3F80u : 0u;
      }
    }

    // O += P.V — P rows wave-private (lgkmcnt orders write->read); V inline
    const int rp = w * 16 + c16;
    const short8 pa0 = *(const short8*)&Pm[rp * 64 + ((quad + rp) & 7) * 8];
    const short8 pa1 = *(const short8*)&Pm[rp * 64 + ((quad + 4 + rp) & 7) * 8];
#pragma unroll
    for (int sub = 0; sub < 4; ++sub) {
      const int rV = sub * 16 + c16;
      const short8 vv0 = *(const short8*)&Vs[vb + rV * 64 + ((quad + rV) & 7) * 8];
      const short8 vv1 = *(const short8*)&Vs[vb + rV * 64 + ((quad + 4 + rV) & 7) * 8];
      oacc[sub] = __builtin_amdgcn_mfma_f32_16x16x32_bf16(pa0, vv0, oacc[sub], 0, 0, 0);
      oacc[sub] = __builtin_amdgcn_mfma_f32_16x16x32_bf16(pa1, vv1, oacc[sub], 0, 0, 0);
    }
  }

  // epilogue: AO[b*2048+s][h*64+d] bf16; C-layout row=quad*4+r (q), col=c16 (d)
  const int b = bh >> 4, hh = bh & 15;
#pragma unroll
  for (int sub = 0; sub < 4; ++sub)
#pragma unroll
    for (int r = 0; r < 4; ++r) {
      const int srow = b * 2048 + q0 + w * 16 + quad * 4 + r;
      AO[(size_t)srow * 1024 + hh * 64 + sub * 16 + c16] = bf16_rne(oacc[sub][r]);
    }
}

// ---------------- kernel 3: output projection, 32x32 bf16 MFMA ---------------
// Same shape/swizzle treatment as k_qkv (1-pass).
__global__ __launch_bounds__(256) void k_out(
    const unsigned short* __restrict__ A, const unsigned short* __restrict__ Bw,
    const float* __restrict__ out_b, float* __restrict__ out) {
  __shared__ unsigned short As[128 * 32], Bs[128 * 32];
  const int tid = threadIdx.x;
  const int lane = tid & 63, wid = tid >> 6;
  const int wm = wid >> 1, wn = wid & 1;
  const int bn = blockIdx.x, bm = blockIdx.y;
  const int l31 = lane & 31, h = lane >> 5;
  const int ldrow = lane >> 2;
  const int ldk = (((lane & 3) - ((lane >> 3) & 3)) & 3) * 8;
  const int rot = (l31 >> 1) & 3;

  f16v acc[2][2];
#pragma unroll
  for (int a = 0; a < 2; ++a)
#pragma unroll
    for (int b = 0; b < 2; ++b)
      acc[a][b] = (f16v){0.f,0.f,0.f,0.f,0.f,0.f,0.f,0.f,0.f,0.f,0.f,0.f,0.f,0.f,0.f,0.f};

  for (int kt = 0; kt < 32; ++kt) {
    const int k0 = kt * 32;
    __syncthreads();
#pragma unroll
    for (int r = 0; r < 2; ++r) {
      const int c = wid + r * 4;
      const int grow = c * 16 + ldrow;
      const size_t ao = (size_t)(bm * 128 + grow) * 1024 + k0 + ldk;
      const size_t bo = (size_t)(bn * 128 + grow) * 1024 + k0 + ldk;
      const int lo = c * 512 + lane * 8;
      gl2lds16(A + ao, &As[lo]);
      gl2lds16(Bw + bo, &Bs[lo]);
    }
    __syncthreads();

#pragma unroll
    for (int ks = 0; ks < 2; ++ks) {
      const int lc = ks * 2 + h;
      const int pcs = ((lc + rot) & 3) * 8;
      short8 af[2], bf_[2];
#pragma unroll
      for (int t = 0; t < 2; ++t) {
        af[t]  = *(const short8*)&As[(wm * 64 + t * 32 + l31) * 32 + pcs];
        bf_[t] = *(const short8*)&Bs[(wn * 64 + t * 32 + l31) * 32 + pcs];
      }
#pragma unroll
      for (int tm = 0; tm < 2; ++tm)
#pragma unroll
        for (int tn = 0; tn < 2; ++tn)
          acc[tm][tn] = __builtin_amdgcn_mfma_f32_32x32x16_bf16(af[tm], bf_[tn], acc[tm][tn], 0, 0, 0);
    }
  }

#pragma unroll
  for (int tm = 0; tm < 2; ++tm) {
#pragma unroll
    for (int tn = 0; tn < 2; ++tn) {
      const int j = bn * 128 + wn * 64 + tn * 32 + l31;
      const float bias = out_b[j];
#pragma unroll
      for (int a = 0; a < 16; ++a) {
        const int i = bm * 128 + wm * 64 + tm * 32 + (a & 3) + 8 * (a >> 2) + 4 * h;
        out[(size_t)i * 1024 + j] = acc[tm][tn][a] + bias;
      }
    }
  }
}

extern "C" void kernel_launch(void* const* d_in, const int* in_sizes, int n_in,
                              void* d_out, int out_size, void* d_ws, size_t ws_size,
                              hipStream_t stream) {
  const float* x     = (const float*)d_in[0];
  const float* qkv_w = (const float*)d_in[3];
  const float* qkv_b = (const float*)d_in[4];
  const float* out_w = (const float*)d_in[5];
  const float* out_b = (const float*)d_in[6];
  float* out = (float*)d_out;

  // workspace carve (ushorts); AO aliases xh (xh dead after k_qkv)
  unsigned short* xh  = (unsigned short*)d_ws;        // 4194304
  unsigned short* xl  = xh + 4194304;                 // 4194304
  unsigned short* wh  = xl + 4194304;                 // 3145728
  unsigned short* wl  = wh + 3145728;                 // 3145728
  unsigned short* woh = wl + 3145728;                 // 1048576
  unsigned short* Vt  = woh + 1048576;                // 4194304
  unsigned short* Qh  = Vt + 4194304;                 // 4194304
  unsigned short* Ql  = Qh + 4194304;                 // 4194304
  unsigned short* Kh  = Ql + 4194304;                 // 4194304
  unsigned short* Kl  = Kh + 4194304;                 // 4194304
  unsigned short* AO  = xh;                           // alias

  k_split<<<8192, 256, 0, stream>>>(x, qkv_w, out_w, xh, xl, wh, wl, woh);
  k_qkv<<<dim3(24, 32), 256, 0, stream>>>(xh, xl, wh, wl, qkv_b, Qh, Ql, Kh, Kl, Vt);
  k_attn<<<dim3(32, 32), 256, 0, stream>>>(Qh, Ql, Kh, Kl, Vt, AO);
  k_out<<<dim3(8, 32), 256, 0, stream>>>(AO, woh, out_b, out);
}